// Round 11
// baseline (411.445 us; speedup 1.0000x reference)
//
#include <hip/hip_runtime.h>
#include <hip/hip_bf16.h>

#define NDIM 512
#define NN   (NDIM * NDIM)

// Workspace:
//   bf16 planes 0..127   : g hi, channel c.  c<64: [i][k]=g[i][k][c]; c>=64: [i][k]=g[k][i][c]
//   bf16 planes 128..255 : g lo, same indexing.              (128 MiB)
//   bf16 t planes @ 256*NN*2 B: t[dd][i][j], 64 planes        (32 MiB)
// Transient: wt1+cb1 at t-plane start (einsum overwrites after stage1 consumes);
//            wt2+cb2 at wsg start (written after einsum consumes g).
// LN folded into GEMMs: out = rstd*(acc - mu*c1) + c2, W' = ln_w*W.

using short8 = __attribute__((ext_vector_type(8))) short;
using f32x4  = __attribute__((ext_vector_type(4))) float;
typedef unsigned int uint32;
typedef unsigned short ushort;

__device__ __forceinline__ float sigmoidf_(float z) { return 1.f / (1.f + __expf(-z)); }
__device__ __forceinline__ uint32 pkbf2(float a, float b) {
    __hip_bfloat162 h = __float22bfloat162_rn(float2{a, b});
    uint32 u; __builtin_memcpy(&u, &h, 4); return u;
}
__device__ __forceinline__ ushort bfbits(float f) {
    __hip_bfloat16 h = __float2bfloat16(f);
    ushort u; __builtin_memcpy(&u, &h, 2); return u;
}
__device__ __forceinline__ float bf2f(ushort h) {
    return __uint_as_float(((uint32)h) << 16);
}

// ---------------------------------------------------------------------------
// Weight prep + csum merged.  Blocks [0, K/2): prep W' hi/lo interleaved.
// Blocks K/2, K/2+1: csum (c1,c2) for P and G halves.
// ---------------------------------------------------------------------------
__global__ void k_prep(const float* __restrict__ Wp, const float* __restrict__ Wg,
                       const float* __restrict__ lnw, const float* __restrict__ lnb,
                       const float* __restrict__ bp, const float* __restrict__ bg,
                       int K, ushort* __restrict__ dst, float* __restrict__ cb)
{
    __shared__ float red[2][2][128];
    const int nbp = (K * 128) / 256;
    const int tid = threadIdx.x;
    if ((int)blockIdx.x < nbp) {
        const int idx = blockIdx.x * 256 + tid;
        const int k = idx >> 7, o = idx & 127;
        const int h = o >> 6, cl = o & 63;
        const int q = cl >> 3, s7 = cl & 7;
        const float wk = lnw[k];
        const float vp = Wp[k * 128 + o] * wk;
        const float vg = Wg[k * 128 + o] * wk;
        const int rowp = (q << 4) + s7;
        const int rowg = (q << 4) + 8 + s7;
        ushort hi;
        hi = bfbits(vp);
        dst[(h * 128 + rowp) * K + k] = hi;
        dst[256 * K + (h * 128 + rowp) * K + k] = bfbits(vp - bf2f(hi));
        hi = bfbits(vg);
        dst[(h * 128 + rowg) * K + k] = hi;
        dst[256 * K + (h * 128 + rowg) * K + k] = bfbits(vg - bf2f(hi));
    } else {
        const int b = blockIdx.x - nbp;
        const float* W = b ? Wg : Wp;
        const float* bias = b ? bg : bp;
        const int o = tid & 127, kh = tid >> 7;
        const int kham = K >> 1;
        const int k0 = kh * kham;
        float c1 = 0.f, c2 = 0.f;
#pragma unroll 8
        for (int k = 0; k < kham; ++k) {
            const float wv = W[(k0 + k) * 128 + o];
            c1 = fmaf(lnw[k0 + k], wv, c1);
            c2 = fmaf(lnb[k0 + k], wv, c2);
        }
        red[kh][0][o] = c1; red[kh][1][o] = c2;
        __syncthreads();
        if (kh == 0) {
            const int base = b ? 256 : 0;
            cb[base + o] = red[0][0][o] + red[1][0][o];
            cb[base + 128 + o] = red[0][1][o] + red[1][1][o] + bias[o];
        }
    }
}

// ---------------------------------------------------------------------------
// Stage 1: 64-position blocks (8192 total), LN-folded dual GEMM, gate,
// bf16 hi/lo plane stores.  5 blocks/CU for TLP.
// ---------------------------------------------------------------------------
__global__ __launch_bounds__(256, 5)
void k_stage1(const float* __restrict__ x, const float* __restrict__ mask,
              const ushort* __restrict__ wt1, const float* __restrict__ cb,
              ushort* __restrict__ wsg)
{
    __shared__ char sbuf[16384];   // A [64 pos][128 feat] bf16 swz; then G u32 [64 ch][64 pos]
    __shared__ float Ms[64], Mu[64], Rs[64];

    const int tid = threadIdx.x;
    const int bx = blockIdx.x;
    const int y  = blockIdx.y;
    const int o0 = y * 64;
    const int w = tid >> 6, l = tid & 63;
    const int mrow = (w & 1) * 32;       // 2 m-frags -> 32 rows
    const int ncol = (w >> 1) * 64;      // 4 n-frags -> 64 B-rows

    long posBase, outBase; int stride;
    if (y == 0) {
        posBase = (long)bx * 64; outBase = posBase; stride = 1;
    } else {
        const int c0 = bx & 511, r0 = (bx >> 9) * 64;
        posBase = (long)r0 * 512 + c0;
        outBase = (long)c0 * 512 + r0;
        stride = 512;
    }

    // --- load x (4 threads/row), cast to bf16 A tile, one-pass stats ---
    {
        const int r = tid >> 2, qf = tid & 3;
        const float* xr = x + (posBase + (long)r * stride) * 128 + qf * 32;
        float v[32]; float s = 0.f, ss = 0.f;
#pragma unroll
        for (int q = 0; q < 8; ++q) {
            const float4 a = ((const float4*)xr)[q];
            v[4*q+0]=a.x; v[4*q+1]=a.y; v[4*q+2]=a.z; v[4*q+3]=a.w;
            s += a.x + a.y + a.z + a.w;
            ss = fmaf(a.x,a.x, fmaf(a.y,a.y, fmaf(a.z,a.z, fmaf(a.w,a.w, ss))));
        }
        s  += __shfl_xor(s, 1);  s  += __shfl_xor(s, 2);
        ss += __shfl_xor(ss, 1); ss += __shfl_xor(ss, 2);
        const float mu = s * (1.f/128.f);
        const float var = ss * (1.f/128.f) - mu*mu;
        const float rstd = rsqrtf(var + 1e-5f);
        if (qf == 0) {
            Ms[r] = mask[posBase + (long)r * stride];
            Mu[r] = mu; Rs[r] = rstd;
        }
#pragma unroll
        for (int jj = 0; jj < 4; ++jj) {
            uint4 pk;
            pk.x = pkbf2(v[jj*8+0], v[jj*8+1]); pk.y = pkbf2(v[jj*8+2], v[jj*8+3]);
            pk.z = pkbf2(v[jj*8+4], v[jj*8+5]); pk.w = pkbf2(v[jj*8+6], v[jj*8+7]);
            const int col = (qf*64 + jj*16) ^ ((r & 15) << 4);
            *(uint4*)(sbuf + r*256 + col) = pk;
        }
    }
    __syncthreads();

    f32x4 acc[2][4];
#pragma unroll
    for (int m = 0; m < 2; ++m)
#pragma unroll
        for (int n = 0; n < 4; ++n) acc[m][n] = (f32x4){0.f,0.f,0.f,0.f};

#pragma unroll
    for (int step = 0; step < 4; ++step) {
        short8 ah[2], bh[4], bl[4];
#pragma unroll
        for (int n = 0; n < 4; ++n) {
            const int row = y*128 + ncol + n*16 + (l & 15);
            const int idx = row*128 + step*32 + (l >> 4)*8;
            bh[n] = *(const short8*)(wt1 + idx);
            bl[n] = *(const short8*)(wt1 + 32768 + idx);
        }
#pragma unroll
        for (int m = 0; m < 2; ++m) {
            const int pos = mrow + m*16 + (l & 15);
            const int col = (step*64 + (l >> 4)*16) ^ ((pos & 15) << 4);
            ah[m] = *(const short8*)(sbuf + pos*256 + col);
        }
#pragma unroll
        for (int m = 0; m < 2; ++m) {
#pragma unroll
            for (int n = 0; n < 4; ++n) {
                acc[m][n] = __builtin_amdgcn_mfma_f32_16x16x32_bf16(ah[m], bh[n], acc[m][n], 0, 0, 0);
                acc[m][n] = __builtin_amdgcn_mfma_f32_16x16x32_bf16(ah[m], bl[n], acc[m][n], 0, 0, 0);
            }
        }
    }
    __syncthreads();   // A reads done; sbuf becomes G (u32-packed hi/lo)

    // --- LN-folded gate, all lanes active (j<8: e 0,1; j>=8: e 2,3) ---
    const int j = l & 15;
    const int e0 = (j >= 8) ? 2 : 0;
#pragma unroll
    for (int m = 0; m < 2; ++m) {
#pragma unroll
        for (int n = 0; n < 4; ++n) {
            const f32x4 a = acc[m][n];
            float pr[4];
#pragma unroll
            for (int e = 0; e < 4; ++e) pr[e] = __shfl_xor(a[e], 8);
            const int cl = (w >> 1)*32 + n*8 + (j & 7);
            const int och = o0 + cl;
            const float c1p = cb[och],       c2p = cb[128 + och];
            const float c1g = cb[256 + och], c2g = cb[384 + och];
            const int p0 = mrow + m*16 + (l >> 4)*4;
            uint2 pk;
#pragma unroll
            for (int t = 0; t < 2; ++t) {
                const int e = e0 + t;
                const float accP = (j >= 8) ? pr[e] : a[e];
                const float accG = (j >= 8) ? a[e] : pr[e];
                const float mu = Mu[p0+e], rstd = Rs[p0+e];
                const float p_ = fmaf(rstd, accP - mu*c1p, c2p);
                const float g_ = fmaf(rstd, accG - mu*c1g, c2g);
                const float g = p_ * sigmoidf_(g_) * Ms[p0+e];
                const ushort hi = bfbits(g);
                const ushort lo = bfbits(g - bf2f(hi));
                ((uint32*)&pk)[t] = ((uint32)hi << 16) | (uint32)lo;
            }
            *(uint2*)(sbuf + cl*256 + ((p0*4) ^ ((cl & 7) << 4)) + e0*4) = pk;
        }
    }
    __syncthreads();

    // --- cooperative plane stores: 128B-contiguous runs per plane ---
#pragma unroll
    for (int it = 0; it < 2; ++it) {
        const int u = it*256 + tid;
        const int c = u >> 3, seg = u & 7;
        ushort* hd = wsg + (long)(o0 + c) * NN + outBase + seg*8;
        ushort* ld = wsg + (long)(128 + o0 + c) * NN + outBase + seg*8;
        short8 hv, lv;
#pragma unroll
        for (int q = 0; q < 2; ++q) {
            const int b = seg*32 + q*16;
            const uint4 w4 = *(const uint4*)(sbuf + c*256 + (b ^ ((c & 7) << 4)));
            hv[q*4+0] = (short)(w4.x >> 16); lv[q*4+0] = (short)(w4.x & 0xffffu);
            hv[q*4+1] = (short)(w4.y >> 16); lv[q*4+1] = (short)(w4.y & 0xffffu);
            hv[q*4+2] = (short)(w4.z >> 16); lv[q*4+2] = (short)(w4.z & 0xffffu);
            hv[q*4+3] = (short)(w4.w >> 16); lv[q*4+3] = (short)(w4.w & 0xffffu);
        }
        *(short8*)hd = hv;
        *(short8*)ld = lv;
    }
}

// ---------------------------------------------------------------------------
// Triangular einsums: 256x256 tile, 8 waves, BK=32, dbuf, hi/lo 3-product.
// Output t stored as bf16 (stage2 casts to bf16 anyway; stats-only impact).
// ---------------------------------------------------------------------------
__global__ __launch_bounds__(512, 1)
void k_einsum(const ushort* __restrict__ wsg, ushort* __restrict__ wst)
{
    const int bid = blockIdx.x;                  // 0..255
    const int nb  = (bid & 7) * 32 + (bid >> 3);
    const int ch  = nb >> 2;
    const int bi  = (nb >> 1) & 1, bj = nb & 1;
    const int pch = (ch < 32) ? ch : ch + 32;

    const ushort* __restrict__ PH = wsg + (long)pch * NN;
    const ushort* __restrict__ QH = wsg + (long)(pch + 32) * NN;
    ushort* __restrict__ T = wst + (long)ch * NN;

    __shared__ char smem[131072];

    const int tid = threadIdx.x;
    const int w = tid >> 6, l = tid & 63;
    const int isB = w >> 2;

    const ushort* sbase = isB ? (QH + (long)bj * 131072) : (PH + (long)bi * 131072);
    int soff[8];
#pragma unroll
    for (int i = 0; i < 8; ++i) {
        const int ci  = ((w & 3) * 8 + i) * 64 + l;
        const int row = ci >> 3, s = ci & 7;
        const int c   = s ^ (row & 7);
        soff[i] = row * 512 + (c >> 2) * (128 * NN) + (c & 3) * 8;
    }
    const int dbase = isB * 32768 + (w & 3) * 8192;

    f32x4 acc[4][8];
#pragma unroll
    for (int m = 0; m < 4; ++m)
#pragma unroll
        for (int n = 0; n < 8; ++n) acc[m][n] = (f32x4){0.f, 0.f, 0.f, 0.f};

    const int wr = w >> 1;
    const int wc = w & 1;

#define STAGE(buf, step)                                                           \
    {                                                                              \
        const int kOff = (step) * 32;                                              \
        _Pragma("unroll")                                                          \
        for (int i = 0; i < 8; ++i) {                                              \
            __builtin_amdgcn_global_load_lds(                                      \
                (const __attribute__((address_space(1))) void*)(sbase + soff[i] + kOff), \
                (__attribute__((address_space(3))) void*)(smem + (buf)*65536 + dbase + i*1024), \
                16, 0, 0);                                                         \
        }                                                                          \
    }

    STAGE(0, 0);
    __syncthreads();

    for (int t = 0; t < 16; ++t) {
        const int cur = t & 1;
        if (t < 15) STAGE(cur ^ 1, t + 1);

        const char* sA = (const char*)smem + cur * 65536;
        const char* sB = sA + 32768;
        const int jc = l >> 4;
        short8 ah[4], al[4];
#pragma unroll
        for (int m = 0; m < 4; ++m) {
            const int r = wr * 64 + m * 16 + (l & 15);
            ah[m] = *(const short8*)(sA + r * 128 + ((jc       ^ (r & 7)) << 4));
            al[m] = *(const short8*)(sA + r * 128 + (((jc | 4) ^ (r & 7)) << 4));
        }
#pragma unroll
        for (int n = 0; n < 8; ++n) {
            const int r = wc * 128 + n * 16 + (l & 15);
            const short8 bh = *(const short8*)(sB + r * 128 + ((jc       ^ (r & 7)) << 4));
            const short8 bl = *(const short8*)(sB + r * 128 + (((jc | 4) ^ (r & 7)) << 4));
#pragma unroll
            for (int m = 0; m < 4; ++m) {
                acc[m][n] = __builtin_amdgcn_mfma_f32_16x16x32_bf16(ah[m], bh, acc[m][n], 0, 0, 0);
                acc[m][n] = __builtin_amdgcn_mfma_f32_16x16x32_bf16(ah[m], bl, acc[m][n], 0, 0, 0);
                acc[m][n] = __builtin_amdgcn_mfma_f32_16x16x32_bf16(al[m], bh, acc[m][n], 0, 0, 0);
            }
        }
        __syncthreads();
    }
#undef STAGE

    const int rbase = bi * 256 + wr * 64;
    const int cbase = bj * 256 + wc * 128;
#pragma unroll
    for (int m = 0; m < 4; ++m) {
#pragma unroll
        for (int n = 0; n < 8; ++n) {
#pragma unroll
            for (int r = 0; r < 4; ++r) {
                const int row = rbase + m * 16 + (l >> 4) * 4 + r;
                const int col = cbase + n * 16 + (l & 15);
                T[(long)row * NDIM + col] = bfbits(acc[m][n][r]);
            }
        }
    }
}

// ---------------------------------------------------------------------------
// Stage 2: 64-position blocks.  Gather bf16 t directly into swizzled A tile;
// LN2 stats from tile; LN-folded dual GEMM; gate; O-buf; coalesced stores.
// ---------------------------------------------------------------------------
__global__ __launch_bounds__(256, 5)
void k_stage2(const ushort* __restrict__ wst, const float* __restrict__ mask,
              const ushort* __restrict__ wt2, const float* __restrict__ cb,
              float* __restrict__ out)
{
    __shared__ char buf[17408];    // A [64 pos][64 ch] bf16 swz @0 (8K); O fp32 [64][68] @0 (17408) after GEMM
    __shared__ float Ms[64], Mu[64], Rs[64];

    const int tid = threadIdx.x;
    const long pos0 = (long)blockIdx.x * 64;
    const int y = blockIdx.y;
    const int o0 = y * 64;
    const int w = tid >> 6, l = tid & 63;
    const int mrow = (w & 1) * 32;
    const int ncol = (w >> 1) * 64;

    // gather: plane d, 8 positions -> scatter into swizzled A tile
#pragma unroll
    for (int q = 0; q < 2; ++q) {
        const int u = q*256 + tid, d = u >> 3, p8 = (u & 7) * 8;
        const short8 v = *(const short8*)(wst + (long)d * NN + pos0 + p8);
#pragma unroll
        for (int e = 0; e < 8; ++e) {
            const int row = p8 + e;
            *(ushort*)(buf + row*128 + ((d*2) ^ ((row & 7) << 4))) = v[e];
        }
    }
    if (tid < 64) Ms[tid] = mask[pos0 + tid];
    __syncthreads();

    // LN2 stats (values stay raw bf16 in tile; LN folded via cb)
    {
        const int r = tid >> 2, qf = tid & 3;
        float s = 0.f, ss = 0.f;
#pragma unroll
        for (int c = 0; c < 2; ++c) {
            const short8 hv = *(const short8*)(buf + r*128 + ((qf*32 + c*16) ^ ((r & 7) << 4)));
#pragma unroll
            for (int e = 0; e < 8; ++e) {
                const float tv = bf2f((ushort)hv[e]);
                s += tv; ss = fmaf(tv, tv, ss);
            }
        }
        s  += __shfl_xor(s, 1);  s  += __shfl_xor(s, 2);
        ss += __shfl_xor(ss, 1); ss += __shfl_xor(ss, 2);
        const float mu = s * (1.f/64.f);
        const float var = ss * (1.f/64.f) - mu*mu;
        const float rstd = rsqrtf(var + 1e-5f);
        if (qf == 0) { Mu[r] = mu; Rs[r] = rstd; }
    }
    __syncthreads();

    f32x4 acc[2][4];
#pragma unroll
    for (int m = 0; m < 2; ++m)
#pragma unroll
        for (int n = 0; n < 4; ++n) acc[m][n] = (f32x4){0.f,0.f,0.f,0.f};

#pragma unroll
    for (int step = 0; step < 2; ++step) {
        short8 ah[2], bh[4], bl[4];
#pragma unroll
        for (int n = 0; n < 4; ++n) {
            const int row = y*128 + ncol + n*16 + (l & 15);
            const int idx = row*64 + step*32 + (l >> 4)*8;
            bh[n] = *(const short8*)(wt2 + idx);
            bl[n] = *(const short8*)(wt2 + 16384 + idx);
        }
#pragma unroll
        for (int m = 0; m < 2; ++m) {
            const int pos = mrow + m*16 + (l & 15);
            const int col = (step*64 + (l >> 4)*16) ^ ((pos & 7) << 4);
            ah[m] = *(const short8*)(buf + pos*128 + col);
        }
#pragma unroll
        for (int m = 0; m < 2; ++m) {
#pragma unroll
            for (int n = 0; n < 4; ++n) {
                acc[m][n] = __builtin_amdgcn_mfma_f32_16x16x32_bf16(ah[m], bh[n], acc[m][n], 0, 0, 0);
                acc[m][n] = __builtin_amdgcn_mfma_f32_16x16x32_bf16(ah[m], bl[n], acc[m][n], 0, 0, 0);
            }
        }
    }
    __syncthreads();   // A reads done; buf becomes O [64][68] fp32

    // LN-folded gate, all lanes active; O[pos][ch]
    const int j = l & 15;
    const int e0 = (j >= 8) ? 2 : 0;
#pragma unroll
    for (int m = 0; m < 2; ++m) {
#pragma unroll
        for (int n = 0; n < 4; ++n) {
            const f32x4 a = acc[m][n];
            float pr[4];
#pragma unroll
            for (int e = 0; e < 4; ++e) pr[e] = __shfl_xor(a[e], 8);
            const int cl = (w >> 1)*32 + n*8 + (j & 7);
            const int och = o0 + cl;
            const float c1p = cb[och],       c2p = cb[128 + och];
            const float c1g = cb[256 + och], c2g = cb[384 + och];
            const int p0 = mrow + m*16 + (l >> 4)*4;
#pragma unroll
            for (int t = 0; t < 2; ++t) {
                const int e = e0 + t;
                const float accP = (j >= 8) ? pr[e] : a[e];
                const float accG = (j >= 8) ? a[e] : pr[e];
                const float mu = Mu[p0+e], rstd = Rs[p0+e];
                const float p_ = fmaf(rstd, accP - mu*c1p, c2p);
                const float g_ = fmaf(rstd, accG - mu*c1g, c2g);
                *(float*)(buf + (p0+e)*272 + cl*4) = p_ * sigmoidf_(g_) * Ms[p0+e];
            }
        }
    }
    __syncthreads();

    // coalesced output stores: 4 float4 per thread
    {
        const int r2 = tid >> 2, h2 = tid & 3;
        float* op = out + (pos0 + r2)*128 + o0 + h2*16;
#pragma unroll
        for (int i = 0; i < 4; ++i)
            *(float4*)(op + i*4) = *(const float4*)(buf + r2*272 + (h2*16 + i*4)*4);
    }
}

// ---------------------------------------------------------------------------
extern "C" void kernel_launch(void* const* d_in, const int* in_sizes, int n_in,
                              void* d_out, int out_size, void* d_ws, size_t ws_size,
                              hipStream_t stream)
{
    const float* x     = (const float*)d_in[0];
    const float* mask  = (const float*)d_in[1];
    const float* ln1_w = (const float*)d_in[2];
    const float* ln1_b = (const float*)d_in[3];
    const float* pi_w  = (const float*)d_in[4];
    const float* pi_b  = (const float*)d_in[5];
    const float* gi_w  = (const float*)d_in[6];
    const float* gi_b  = (const float*)d_in[7];
    const float* ln2_w = (const float*)d_in[8];
    const float* ln2_b = (const float*)d_in[9];
    const float* po_w  = (const float*)d_in[10];
    const float* po_b  = (const float*)d_in[11];
    const float* go_w  = (const float*)d_in[12];
    const float* go_b  = (const float*)d_in[13];

    ushort* wsg  = (ushort*)d_ws;                              // 256 bf16 g planes
    ushort* wstu = (ushort*)((char*)d_ws + (long)256 * NN * 2); // 64 bf16 t planes
    ushort* wt1  = wstu;                                        // transient (pre-einsum)
    float*  cb1  = (float*)(wt1 + 65536);
    ushort* wt2  = wsg;                                         // transient (post-einsum)
    float*  cb2  = (float*)(wt2 + 32768);

    k_prep<<<66, 256, 0, stream>>>(pi_w, gi_w, ln1_w, ln1_b, pi_b, gi_b, 128, wt1, cb1);
    k_stage1<<<dim3(4096, 2), 256, 0, stream>>>(x, mask, wt1, cb1, wsg);
    k_einsum<<<256, 512, 0, stream>>>(wsg, wstu);
    k_prep<<<34, 256, 0, stream>>>(po_w, go_w, ln2_w, ln2_b, po_b, go_b, 64, wt2, cb2);
    k_stage2<<<dim3(4096, 2), 256, 0, stream>>>(wstu, mask, wt2, cb2, (float*)d_out);
}

// Round 12
// 360.248 us; speedup vs baseline: 1.1421x; 1.1421x over previous
//
#include <hip/hip_runtime.h>
#include <hip/hip_bf16.h>

#define NDIM 512
#define NN   (NDIM * NDIM)

// Workspace:
//   bf16 planes 0..127   : g hi, channel c.  c<64: [i][k]=g[i][k][c]; c>=64: [i][k]=g[k][i][c]
//   bf16 planes 128..255 : g lo, same indexing.              (128 MiB)
//   bf16 t planes @ 256*NN*2 B: t[dd][i][j], 64 planes        (32 MiB)
// Transient: wt1+cb1 at t-plane start; wt2+cb2 at wsg start (post-einsum).
// LN folded into GEMMs: out = rstd*(acc - mu*c1) + c2, W' = ln_w*W.

using short8 = __attribute__((ext_vector_type(8))) short;
using f32x4  = __attribute__((ext_vector_type(4))) float;
typedef unsigned int uint32;
typedef unsigned short ushort;

__device__ __forceinline__ float sigmoidf_(float z) { return 1.f / (1.f + __expf(-z)); }
__device__ __forceinline__ uint32 pkbf2(float a, float b) {
    __hip_bfloat162 h = __float22bfloat162_rn(float2{a, b});
    uint32 u; __builtin_memcpy(&u, &h, 4); return u;
}
__device__ __forceinline__ ushort bfbits(float f) {
    __hip_bfloat16 h = __float2bfloat16(f);
    ushort u; __builtin_memcpy(&u, &h, 2); return u;
}
__device__ __forceinline__ float bf2f(ushort h) {
    return __uint_as_float(((uint32)h) << 16);
}

// ---------------------------------------------------------------------------
// Weight prep + csum merged.  Blocks [0, K/2): prep W' hi/lo interleaved.
// Blocks K/2, K/2+1: csum (c1,c2) for P and G halves.
// ---------------------------------------------------------------------------
__global__ void k_prep(const float* __restrict__ Wp, const float* __restrict__ Wg,
                       const float* __restrict__ lnw, const float* __restrict__ lnb,
                       const float* __restrict__ bp, const float* __restrict__ bg,
                       int K, ushort* __restrict__ dst, float* __restrict__ cb)
{
    __shared__ float red[2][2][128];
    const int nbp = (K * 128) / 256;
    const int tid = threadIdx.x;
    if ((int)blockIdx.x < nbp) {
        const int idx = blockIdx.x * 256 + tid;
        const int k = idx >> 7, o = idx & 127;
        const int h = o >> 6, cl = o & 63;
        const int q = cl >> 3, s7 = cl & 7;
        const float wk = lnw[k];
        const float vp = Wp[k * 128 + o] * wk;
        const float vg = Wg[k * 128 + o] * wk;
        const int rowp = (q << 4) + s7;
        const int rowg = (q << 4) + 8 + s7;
        ushort hi;
        hi = bfbits(vp);
        dst[(h * 128 + rowp) * K + k] = hi;
        dst[256 * K + (h * 128 + rowp) * K + k] = bfbits(vp - bf2f(hi));
        hi = bfbits(vg);
        dst[(h * 128 + rowg) * K + k] = hi;
        dst[256 * K + (h * 128 + rowg) * K + k] = bfbits(vg - bf2f(hi));
    } else {
        const int b = blockIdx.x - nbp;
        const float* W = b ? Wg : Wp;
        const float* bias = b ? bg : bp;
        const int o = tid & 127, kh = tid >> 7;
        const int kham = K >> 1;
        const int k0 = kh * kham;
        float c1 = 0.f, c2 = 0.f;
#pragma unroll 8
        for (int k = 0; k < kham; ++k) {
            const float wv = W[(k0 + k) * 128 + o];
            c1 = fmaf(lnw[k0 + k], wv, c1);
            c2 = fmaf(lnb[k0 + k], wv, c2);
        }
        red[kh][0][o] = c1; red[kh][1][o] = c2;
        __syncthreads();
        if (kh == 0) {
            const int base = b ? 256 : 0;
            cb[base + o] = red[0][0][o] + red[1][0][o];
            cb[base + 128 + o] = red[0][1][o] + red[1][1][o] + bias[o];
        }
    }
}

// ---------------------------------------------------------------------------
// Stage 1 (r10 config): 128-position blocks, LN-folded dual GEMM, occ 4.
// ---------------------------------------------------------------------------
__global__ __launch_bounds__(256, 4)
void k_stage1(const float* __restrict__ x, const float* __restrict__ mask,
              const ushort* __restrict__ wt1, const float* __restrict__ cb,
              ushort* __restrict__ wsg)
{
    __shared__ char sbuf[32768];   // A tile bf16(x) swz; later G u32-packed
    __shared__ float Ms[128], Mu[128], Rs[128];

    const int tid = threadIdx.x;
    const int bx = blockIdx.x;
    const int y  = blockIdx.y;
    const int o0 = y * 64;
    const int w = tid >> 6, l = tid & 63;
    const int mrow = (w & 1) * 64, ncol = (w >> 1) * 64;

    long posBase, outBase; int stride;
    if (y == 0) {
        posBase = ((long)(bx >> 2)) * 512 + (long)(bx & 3) * 128;
        outBase = posBase; stride = 1;
    } else {
        posBase = ((long)(bx >> 9)) * 65536 + (bx & 511);
        outBase = (long)(bx & 511) * 512 + ((bx >> 9) * 128);
        stride = 512;
    }

    // --- B prefetch for step 0 (overlaps x-load/LN) ---
    short8 bh[2][4], bl[2][4];
#pragma unroll
    for (int n = 0; n < 4; ++n) {
        const int row = y*128 + ncol + n*16 + (l & 15);
        const int idx = row*128 + (l >> 4)*8;
        bh[0][n] = *(const short8*)(wt1 + idx);
        bl[0][n] = *(const short8*)(wt1 + 32768 + idx);
    }

    // --- load x, cast to bf16 A tile, one-pass stats ---
    {
        const int r = tid >> 1, hf = tid & 1;
        const float* xr = x + (posBase + (long)r * stride) * 128 + hf * 64;
        float s = 0.f, ss = 0.f;
#pragma unroll
        for (int q = 0; q < 8; ++q) {
            const float4 a = ((const float4*)xr)[2*q];
            const float4 b = ((const float4*)xr)[2*q+1];
            s  += a.x + a.y + a.z + a.w + b.x + b.y + b.z + b.w;
            ss = fmaf(a.x,a.x, fmaf(a.y,a.y, fmaf(a.z,a.z, fmaf(a.w,a.w, ss))));
            ss = fmaf(b.x,b.x, fmaf(b.y,b.y, fmaf(b.z,b.z, fmaf(b.w,b.w, ss))));
            uint4 pk;
            pk.x = pkbf2(a.x, a.y); pk.y = pkbf2(a.z, a.w);
            pk.z = pkbf2(b.x, b.y); pk.w = pkbf2(b.z, b.w);
            const int col = (hf*128 + q*16) ^ ((r & 15) << 4);
            *(uint4*)(sbuf + r*256 + col) = pk;
        }
        s  += __shfl_xor(s, 1);
        ss += __shfl_xor(ss, 1);
        const float mu = s * (1.f/128.f);
        const float var = ss * (1.f/128.f) - mu*mu;
        const float rstd = rsqrtf(var + 1e-5f);
        if (hf == 0) {
            Ms[r] = mask[posBase + (long)r * stride];
            Mu[r] = mu; Rs[r] = rstd;
        }
    }
    __syncthreads();

    f32x4 acc[4][4];
#pragma unroll
    for (int m = 0; m < 4; ++m)
#pragma unroll
        for (int n = 0; n < 4; ++n) acc[m][n] = (f32x4){0.f,0.f,0.f,0.f};

#pragma unroll
    for (int step = 0; step < 4; ++step) {
        if (step < 3) {
            const int s1 = step + 1;
#pragma unroll
            for (int n = 0; n < 4; ++n) {
                const int row = y*128 + ncol + n*16 + (l & 15);
                const int idx = row*128 + s1*32 + (l >> 4)*8;
                bh[s1 & 1][n] = *(const short8*)(wt1 + idx);
                bl[s1 & 1][n] = *(const short8*)(wt1 + 32768 + idx);
            }
        }
        short8 ah[4];
#pragma unroll
        for (int m = 0; m < 4; ++m) {
            const int pos = mrow + m*16 + (l & 15);
            const int col = (step*64 + (l >> 4)*16) ^ ((pos & 15) << 4);
            ah[m] = *(const short8*)(sbuf + pos*256 + col);
        }
#pragma unroll
        for (int m = 0; m < 4; ++m) {
#pragma unroll
            for (int n = 0; n < 4; ++n) {
                acc[m][n] = __builtin_amdgcn_mfma_f32_16x16x32_bf16(ah[m], bh[step & 1][n], acc[m][n], 0, 0, 0);
                acc[m][n] = __builtin_amdgcn_mfma_f32_16x16x32_bf16(ah[m], bl[step & 1][n], acc[m][n], 0, 0, 0);
            }
        }
    }
    __syncthreads();   // A reads done; sbuf becomes G (u32-packed hi/lo)

    // --- LN-folded gate, all lanes active ---
    const int j = l & 15;
    const int e0 = (j >= 8) ? 2 : 0;
#pragma unroll
    for (int m = 0; m < 4; ++m) {
#pragma unroll
        for (int n = 0; n < 4; ++n) {
            const f32x4 a = acc[m][n];
            float pr[4];
#pragma unroll
            for (int e = 0; e < 4; ++e) pr[e] = __shfl_xor(a[e], 8);
            const int cl = (w >> 1)*32 + n*8 + (j & 7);
            const int och = o0 + cl;
            const float c1p = cb[och],       c2p = cb[128 + och];
            const float c1g = cb[256 + och], c2g = cb[384 + och];
            const int p0 = mrow + m*16 + (l >> 4)*4;
            uint2 pk;
#pragma unroll
            for (int t = 0; t < 2; ++t) {
                const int e = e0 + t;
                const float accP = (j >= 8) ? pr[e] : a[e];
                const float accG = (j >= 8) ? a[e] : pr[e];
                const float mu = Mu[p0+e], rstd = Rs[p0+e];
                const float p_ = fmaf(rstd, accP - mu*c1p, c2p);
                const float g_ = fmaf(rstd, accG - mu*c1g, c2g);
                const float g = p_ * sigmoidf_(g_) * Ms[p0+e];
                const ushort hi = bfbits(g);
                const ushort lo = bfbits(g - bf2f(hi));
                ((uint32*)&pk)[t] = ((uint32)hi << 16) | (uint32)lo;
            }
            *(uint2*)(sbuf + cl*512 + ((p0*4) ^ ((cl & 7) << 4)) + e0*4) = pk;
        }
    }
    __syncthreads();

    // --- cooperative plane stores: 256B-contiguous runs per plane ---
#pragma unroll
    for (int it = 0; it < 2; ++it) {
        const int u = it*256 + tid;
        const int c = u >> 3, seg = u & 7;
        ushort* hd = wsg + (long)(o0 + c) * NN + outBase + seg*16;
        ushort* ld = wsg + (long)(128 + o0 + c) * NN + outBase + seg*16;
#pragma unroll
        for (int half = 0; half < 2; ++half) {
            short8 hv, lv;
#pragma unroll
            for (int q = 0; q < 2; ++q) {
                const int b = seg*64 + half*32 + q*16;
                const uint4 w4 = *(const uint4*)(sbuf + c*512 + (b ^ ((c & 7) << 4)));
                hv[q*4+0] = (short)(w4.x >> 16); lv[q*4+0] = (short)(w4.x & 0xffffu);
                hv[q*4+1] = (short)(w4.y >> 16); lv[q*4+1] = (short)(w4.y & 0xffffu);
                hv[q*4+2] = (short)(w4.z >> 16); lv[q*4+2] = (short)(w4.z & 0xffffu);
                hv[q*4+3] = (short)(w4.w >> 16); lv[q*4+3] = (short)(w4.w & 0xffffu);
            }
            *(short8*)(hd + half*8) = hv;
            *(short8*)(ld + half*8) = lv;
        }
    }
}

// ---------------------------------------------------------------------------
// Triangular einsums: 256x256 tile, 8 waves, BK=32, dbuf, hi/lo 3-product.
// Output t stored as bf16.
// ---------------------------------------------------------------------------
__global__ __launch_bounds__(512, 1)
void k_einsum(const ushort* __restrict__ wsg, ushort* __restrict__ wst)
{
    const int bid = blockIdx.x;                  // 0..255
    const int nb  = (bid & 7) * 32 + (bid >> 3);
    const int ch  = nb >> 2;
    const int bi  = (nb >> 1) & 1, bj = nb & 1;
    const int pch = (ch < 32) ? ch : ch + 32;

    const ushort* __restrict__ PH = wsg + (long)pch * NN;
    const ushort* __restrict__ QH = wsg + (long)(pch + 32) * NN;
    ushort* __restrict__ T = wst + (long)ch * NN;

    __shared__ char smem[131072];

    const int tid = threadIdx.x;
    const int w = tid >> 6, l = tid & 63;
    const int isB = w >> 2;

    const ushort* sbase = isB ? (QH + (long)bj * 131072) : (PH + (long)bi * 131072);
    int soff[8];
#pragma unroll
    for (int i = 0; i < 8; ++i) {
        const int ci  = ((w & 3) * 8 + i) * 64 + l;
        const int row = ci >> 3, s = ci & 7;
        const int c   = s ^ (row & 7);
        soff[i] = row * 512 + (c >> 2) * (128 * NN) + (c & 3) * 8;
    }
    const int dbase = isB * 32768 + (w & 3) * 8192;

    f32x4 acc[4][8];
#pragma unroll
    for (int m = 0; m < 4; ++m)
#pragma unroll
        for (int n = 0; n < 8; ++n) acc[m][n] = (f32x4){0.f, 0.f, 0.f, 0.f};

    const int wr = w >> 1;
    const int wc = w & 1;

#define STAGE(buf, step)                                                           \
    {                                                                              \
        const int kOff = (step) * 32;                                              \
        _Pragma("unroll")                                                          \
        for (int i = 0; i < 8; ++i) {                                              \
            __builtin_amdgcn_global_load_lds(                                      \
                (const __attribute__((address_space(1))) void*)(sbase + soff[i] + kOff), \
                (__attribute__((address_space(3))) void*)(smem + (buf)*65536 + dbase + i*1024), \
                16, 0, 0);                                                         \
        }                                                                          \
    }

    STAGE(0, 0);
    __syncthreads();

    for (int t = 0; t < 16; ++t) {
        const int cur = t & 1;
        if (t < 15) STAGE(cur ^ 1, t + 1);

        const char* sA = (const char*)smem + cur * 65536;
        const char* sB = sA + 32768;
        const int jc = l >> 4;
        short8 ah[4], al[4];
#pragma unroll
        for (int m = 0; m < 4; ++m) {
            const int r = wr * 64 + m * 16 + (l & 15);
            ah[m] = *(const short8*)(sA + r * 128 + ((jc       ^ (r & 7)) << 4));
            al[m] = *(const short8*)(sA + r * 128 + (((jc | 4) ^ (r & 7)) << 4));
        }
#pragma unroll
        for (int n = 0; n < 8; ++n) {
            const int r = wc * 128 + n * 16 + (l & 15);
            const short8 bh = *(const short8*)(sB + r * 128 + ((jc       ^ (r & 7)) << 4));
            const short8 bl = *(const short8*)(sB + r * 128 + (((jc | 4) ^ (r & 7)) << 4));
#pragma unroll
            for (int m = 0; m < 4; ++m) {
                acc[m][n] = __builtin_amdgcn_mfma_f32_16x16x32_bf16(ah[m], bh, acc[m][n], 0, 0, 0);
                acc[m][n] = __builtin_amdgcn_mfma_f32_16x16x32_bf16(ah[m], bl, acc[m][n], 0, 0, 0);
                acc[m][n] = __builtin_amdgcn_mfma_f32_16x16x32_bf16(al[m], bh, acc[m][n], 0, 0, 0);
            }
        }
        __syncthreads();
    }
#undef STAGE

    const int rbase = bi * 256 + wr * 64;
    const int cbase = bj * 256 + wc * 128;
#pragma unroll
    for (int m = 0; m < 4; ++m) {
#pragma unroll
        for (int n = 0; n < 8; ++n) {
#pragma unroll
            for (int r = 0; r < 4; ++r) {
                const int row = rbase + m * 16 + (l >> 4) * 4 + r;
                const int col = cbase + n * 16 + (l & 15);
                T[(long)row * NDIM + col] = bfbits(acc[m][n][r]);
            }
        }
    }
}

// ---------------------------------------------------------------------------
// Stage 2: 64-position blocks.  Gather bf16 t directly into swizzled A tile;
// LN2 stats from tile; LN-folded dual GEMM; gate; O-buf; coalesced stores.
// ---------------------------------------------------------------------------
__global__ __launch_bounds__(256, 5)
void k_stage2(const ushort* __restrict__ wst, const float* __restrict__ mask,
              const ushort* __restrict__ wt2, const float* __restrict__ cb,
              float* __restrict__ out)
{
    __shared__ char buf[17408];    // A [64 pos][64 ch] bf16 swz (8K); then O fp32 [64][68]
    __shared__ float Ms[64], Mu[64], Rs[64];

    const int tid = threadIdx.x;
    const long pos0 = (long)blockIdx.x * 64;
    const int y = blockIdx.y;
    const int o0 = y * 64;
    const int w = tid >> 6, l = tid & 63;
    const int mrow = (w & 1) * 32;
    const int ncol = (w >> 1) * 64;

    // gather: plane d, 8 positions -> scatter into swizzled A tile
#pragma unroll
    for (int q = 0; q < 2; ++q) {
        const int u = q*256 + tid, d = u >> 3, p8 = (u & 7) * 8;
        const short8 v = *(const short8*)(wst + (long)d * NN + pos0 + p8);
#pragma unroll
        for (int e = 0; e < 8; ++e) {
            const int row = p8 + e;
            *(ushort*)(buf + row*128 + ((d*2) ^ ((row & 7) << 4))) = v[e];
        }
    }
    if (tid < 64) Ms[tid] = mask[pos0 + tid];
    __syncthreads();

    // LN2 stats (values stay raw bf16 in tile; LN folded via cb)
    {
        const int r = tid >> 2, qf = tid & 3;
        float s = 0.f, ss = 0.f;
#pragma unroll
        for (int c = 0; c < 2; ++c) {
            const short8 hv = *(const short8*)(buf + r*128 + ((qf*32 + c*16) ^ ((r & 7) << 4)));
#pragma unroll
            for (int e = 0; e < 8; ++e) {
                const float tv = bf2f((ushort)hv[e]);
                s += tv; ss = fmaf(tv, tv, ss);
            }
        }
        s  += __shfl_xor(s, 1);  s  += __shfl_xor(s, 2);
        ss += __shfl_xor(ss, 1); ss += __shfl_xor(ss, 2);
        const float mu = s * (1.f/64.f);
        const float var = ss * (1.f/64.f) - mu*mu;
        const float rstd = rsqrtf(var + 1e-5f);
        if (qf == 0) { Mu[r] = mu; Rs[r] = rstd; }
    }
    __syncthreads();

    f32x4 acc[2][4];
#pragma unroll
    for (int m = 0; m < 2; ++m)
#pragma unroll
        for (int n = 0; n < 4; ++n) acc[m][n] = (f32x4){0.f,0.f,0.f,0.f};

#pragma unroll
    for (int step = 0; step < 2; ++step) {
        short8 ah[2], bh[4], bl[4];
#pragma unroll
        for (int n = 0; n < 4; ++n) {
            const int row = y*128 + ncol + n*16 + (l & 15);
            const int idx = row*64 + step*32 + (l >> 4)*8;
            bh[n] = *(const short8*)(wt2 + idx);
            bl[n] = *(const short8*)(wt2 + 16384 + idx);
        }
#pragma unroll
        for (int m = 0; m < 2; ++m) {
            const int pos = mrow + m*16 + (l & 15);
            const int col = (step*64 + (l >> 4)*16) ^ ((pos & 7) << 4);
            ah[m] = *(const short8*)(buf + pos*128 + col);
        }
#pragma unroll
        for (int m = 0; m < 2; ++m) {
#pragma unroll
            for (int n = 0; n < 4; ++n) {
                acc[m][n] = __builtin_amdgcn_mfma_f32_16x16x32_bf16(ah[m], bh[n], acc[m][n], 0, 0, 0);
                acc[m][n] = __builtin_amdgcn_mfma_f32_16x16x32_bf16(ah[m], bl[n], acc[m][n], 0, 0, 0);
            }
        }
    }
    __syncthreads();   // A reads done; buf becomes O [64][68] fp32

    // LN-folded gate, all lanes active; O[pos][ch]
    const int j = l & 15;
    const int e0 = (j >= 8) ? 2 : 0;
#pragma unroll
    for (int m = 0; m < 2; ++m) {
#pragma unroll
        for (int n = 0; n < 4; ++n) {
            const f32x4 a = acc[m][n];
            float pr[4];
#pragma unroll
            for (int e = 0; e < 4; ++e) pr[e] = __shfl_xor(a[e], 8);
            const int cl = (w >> 1)*32 + n*8 + (j & 7);
            const int och = o0 + cl;
            const float c1p = cb[och],       c2p = cb[128 + och];
            const float c1g = cb[256 + och], c2g = cb[384 + och];
            const int p0 = mrow + m*16 + (l >> 4)*4;
#pragma unroll
            for (int t = 0; t < 2; ++t) {
                const int e = e0 + t;
                const float accP = (j >= 8) ? pr[e] : a[e];
                const float accG = (j >= 8) ? a[e] : pr[e];
                const float mu = Mu[p0+e], rstd = Rs[p0+e];
                const float p_ = fmaf(rstd, accP - mu*c1p, c2p);
                const float g_ = fmaf(rstd, accG - mu*c1g, c2g);
                *(float*)(buf + (p0+e)*272 + cl*4) = p_ * sigmoidf_(g_) * Ms[p0+e];
            }
        }
    }
    __syncthreads();

    // coalesced output stores: 4 float4 per thread
    {
        const int r2 = tid >> 2, h2 = tid & 3;
        float* op = out + (pos0 + r2)*128 + o0 + h2*16;
#pragma unroll
        for (int i = 0; i < 4; ++i)
            *(float4*)(op + i*4) = *(const float4*)(buf + r2*272 + (h2*16 + i*4)*4);
    }
}

// ---------------------------------------------------------------------------
extern "C" void kernel_launch(void* const* d_in, const int* in_sizes, int n_in,
                              void* d_out, int out_size, void* d_ws, size_t ws_size,
                              hipStream_t stream)
{
    const float* x     = (const float*)d_in[0];
    const float* mask  = (const float*)d_in[1];
    const float* ln1_w = (const float*)d_in[2];
    const float* ln1_b = (const float*)d_in[3];
    const float* pi_w  = (const float*)d_in[4];
    const float* pi_b  = (const float*)d_in[5];
    const float* gi_w  = (const float*)d_in[6];
    const float* gi_b  = (const float*)d_in[7];
    const float* ln2_w = (const float*)d_in[8];
    const float* ln2_b = (const float*)d_in[9];
    const float* po_w  = (const float*)d_in[10];
    const float* po_b  = (const float*)d_in[11];
    const float* go_w  = (const float*)d_in[12];
    const float* go_b  = (const float*)d_in[13];

    ushort* wsg  = (ushort*)d_ws;                               // 256 bf16 g planes
    ushort* wstu = (ushort*)((char*)d_ws + (long)256 * NN * 2); // 64 bf16 t planes
    ushort* wt1  = wstu;                                        // transient (pre-einsum)
    float*  cb1  = (float*)(wt1 + 65536);
    ushort* wt2  = wsg;                                         // transient (post-einsum)
    float*  cb2  = (float*)(wt2 + 32768);

    k_prep<<<66, 256, 0, stream>>>(pi_w, gi_w, ln1_w, ln1_b, pi_b, gi_b, 128, wt1, cb1);
    k_stage1<<<dim3(2048, 2), 256, 0, stream>>>(x, mask, wt1, cb1, wsg);
    k_einsum<<<256, 512, 0, stream>>>(wsg, wstu);
    k_prep<<<34, 256, 0, stream>>>(po_w, go_w, ln2_w, ln2_b, po_b, go_b, 64, wt2, cb2);
    k_stage2<<<dim3(4096, 2), 256, 0, stream>>>(wstu, mask, wt2, cb2, (float*)d_out);
}

// Round 13
// 359.609 us; speedup vs baseline: 1.1441x; 1.0018x over previous
//
#include <hip/hip_runtime.h>
#include <hip/hip_bf16.h>

#define NDIM 512
#define NN   (NDIM * NDIM)

// Workspace:
//   bf16 planes 0..127   : g hi, channel c.  c<64: [i][k]=g[i][k][c]; c>=64: [i][k]=g[k][i][c]
//   bf16 planes 128..255 : g lo, same indexing.              (128 MiB)
//   bf16 t planes @ 256*NN*2 B: t[dd][i][j], 64 planes        (32 MiB)
// Transient: wt1+cb1 at t-plane start; wt2+cb2 at wsg start (post-einsum).
// LN folded into GEMMs: out = rstd*(acc - mu*c1) + c2, W' = ln_w*W.

using short8 = __attribute__((ext_vector_type(8))) short;
using f32x4  = __attribute__((ext_vector_type(4))) float;
typedef unsigned int uint32;
typedef unsigned short ushort;

__device__ __forceinline__ float sigmoidf_(float z) { return 1.f / (1.f + __expf(-z)); }
__device__ __forceinline__ uint32 pkbf2(float a, float b) {
    __hip_bfloat162 h = __float22bfloat162_rn(float2{a, b});
    uint32 u; __builtin_memcpy(&u, &h, 4); return u;
}
__device__ __forceinline__ ushort bfbits(float f) {
    __hip_bfloat16 h = __float2bfloat16(f);
    ushort u; __builtin_memcpy(&u, &h, 2); return u;
}
__device__ __forceinline__ float bf2f(ushort h) {
    return __uint_as_float(((uint32)h) << 16);
}

// ---------------------------------------------------------------------------
// Weight prep + csum merged.
// ---------------------------------------------------------------------------
__global__ void k_prep(const float* __restrict__ Wp, const float* __restrict__ Wg,
                       const float* __restrict__ lnw, const float* __restrict__ lnb,
                       const float* __restrict__ bp, const float* __restrict__ bg,
                       int K, ushort* __restrict__ dst, float* __restrict__ cb)
{
    __shared__ float red[2][2][128];
    const int nbp = (K * 128) / 256;
    const int tid = threadIdx.x;
    if ((int)blockIdx.x < nbp) {
        const int idx = blockIdx.x * 256 + tid;
        const int k = idx >> 7, o = idx & 127;
        const int h = o >> 6, cl = o & 63;
        const int q = cl >> 3, s7 = cl & 7;
        const float wk = lnw[k];
        const float vp = Wp[k * 128 + o] * wk;
        const float vg = Wg[k * 128 + o] * wk;
        const int rowp = (q << 4) + s7;
        const int rowg = (q << 4) + 8 + s7;
        ushort hi;
        hi = bfbits(vp);
        dst[(h * 128 + rowp) * K + k] = hi;
        dst[256 * K + (h * 128 + rowp) * K + k] = bfbits(vp - bf2f(hi));
        hi = bfbits(vg);
        dst[(h * 128 + rowg) * K + k] = hi;
        dst[256 * K + (h * 128 + rowg) * K + k] = bfbits(vg - bf2f(hi));
    } else {
        const int b = blockIdx.x - nbp;
        const float* W = b ? Wg : Wp;
        const float* bias = b ? bg : bp;
        const int o = tid & 127, kh = tid >> 7;
        const int kham = K >> 1;
        const int k0 = kh * kham;
        float c1 = 0.f, c2 = 0.f;
#pragma unroll 8
        for (int k = 0; k < kham; ++k) {
            const float wv = W[(k0 + k) * 128 + o];
            c1 = fmaf(lnw[k0 + k], wv, c1);
            c2 = fmaf(lnb[k0 + k], wv, c2);
        }
        red[kh][0][o] = c1; red[kh][1][o] = c2;
        __syncthreads();
        if (kh == 0) {
            const int base = b ? 256 : 0;
            cb[base + o] = red[0][0][o] + red[1][0][o];
            cb[base + 128 + o] = red[0][1][o] + red[1][1][o] + bias[o];
        }
    }
}

// ---------------------------------------------------------------------------
// Stage 1: 128-position blocks, LN-folded dual GEMM, occ 4.
// 1D grid with twin-pairing: (bx,y=0) and (bx,y=1) are 8 block-IDs apart ->
// same XCD -> second twin's x-reads L2-hit.
// ---------------------------------------------------------------------------
__global__ __launch_bounds__(256, 4)
void k_stage1(const float* __restrict__ x, const float* __restrict__ mask,
              const ushort* __restrict__ wt1, const float* __restrict__ cb,
              ushort* __restrict__ wsg)
{
    __shared__ char sbuf[32768];   // A tile bf16(x) swz; later G u32-packed
    __shared__ float Ms[128], Mu[128], Rs[128];

    const int tid = threadIdx.x;
    const int g  = blockIdx.x;
    const int y  = (g >> 3) & 1;
    const int bx = (g & 7) | ((g >> 4) << 3);
    const int o0 = y * 64;
    const int w = tid >> 6, l = tid & 63;
    const int mrow = (w & 1) * 64, ncol = (w >> 1) * 64;

    long posBase, outBase; int stride;
    if (y == 0) {
        posBase = ((long)(bx >> 2)) * 512 + (long)(bx & 3) * 128;
        outBase = posBase; stride = 1;
    } else {
        posBase = ((long)(bx >> 9)) * 65536 + (bx & 511);
        outBase = (long)(bx & 511) * 512 + ((bx >> 9) * 128);
        stride = 512;
    }

    // --- B prefetch for step 0 (overlaps x-load/LN) ---
    short8 bh[2][4], bl[2][4];
#pragma unroll
    for (int n = 0; n < 4; ++n) {
        const int row = y*128 + ncol + n*16 + (l & 15);
        const int idx = row*128 + (l >> 4)*8;
        bh[0][n] = *(const short8*)(wt1 + idx);
        bl[0][n] = *(const short8*)(wt1 + 32768 + idx);
    }

    // --- load x, cast to bf16 A tile, one-pass stats ---
    {
        const int r = tid >> 1, hf = tid & 1;
        const float* xr = x + (posBase + (long)r * stride) * 128 + hf * 64;
        float s = 0.f, ss = 0.f;
#pragma unroll
        for (int q = 0; q < 8; ++q) {
            const float4 a = ((const float4*)xr)[2*q];
            const float4 b = ((const float4*)xr)[2*q+1];
            s  += a.x + a.y + a.z + a.w + b.x + b.y + b.z + b.w;
            ss = fmaf(a.x,a.x, fmaf(a.y,a.y, fmaf(a.z,a.z, fmaf(a.w,a.w, ss))));
            ss = fmaf(b.x,b.x, fmaf(b.y,b.y, fmaf(b.z,b.z, fmaf(b.w,b.w, ss))));
            uint4 pk;
            pk.x = pkbf2(a.x, a.y); pk.y = pkbf2(a.z, a.w);
            pk.z = pkbf2(b.x, b.y); pk.w = pkbf2(b.z, b.w);
            const int col = (hf*128 + q*16) ^ ((r & 15) << 4);
            *(uint4*)(sbuf + r*256 + col) = pk;
        }
        s  += __shfl_xor(s, 1);
        ss += __shfl_xor(ss, 1);
        const float mu = s * (1.f/128.f);
        const float var = ss * (1.f/128.f) - mu*mu;
        const float rstd = rsqrtf(var + 1e-5f);
        if (hf == 0) {
            Ms[r] = mask[posBase + (long)r * stride];
            Mu[r] = mu; Rs[r] = rstd;
        }
    }
    __syncthreads();

    f32x4 acc[4][4];
#pragma unroll
    for (int m = 0; m < 4; ++m)
#pragma unroll
        for (int n = 0; n < 4; ++n) acc[m][n] = (f32x4){0.f,0.f,0.f,0.f};

#pragma unroll
    for (int step = 0; step < 4; ++step) {
        if (step < 3) {
            const int s1 = step + 1;
#pragma unroll
            for (int n = 0; n < 4; ++n) {
                const int row = y*128 + ncol + n*16 + (l & 15);
                const int idx = row*128 + s1*32 + (l >> 4)*8;
                bh[s1 & 1][n] = *(const short8*)(wt1 + idx);
                bl[s1 & 1][n] = *(const short8*)(wt1 + 32768 + idx);
            }
        }
        short8 ah[4];
#pragma unroll
        for (int m = 0; m < 4; ++m) {
            const int pos = mrow + m*16 + (l & 15);
            const int col = (step*64 + (l >> 4)*16) ^ ((pos & 15) << 4);
            ah[m] = *(const short8*)(sbuf + pos*256 + col);
        }
#pragma unroll
        for (int m = 0; m < 4; ++m) {
#pragma unroll
            for (int n = 0; n < 4; ++n) {
                acc[m][n] = __builtin_amdgcn_mfma_f32_16x16x32_bf16(ah[m], bh[step & 1][n], acc[m][n], 0, 0, 0);
                acc[m][n] = __builtin_amdgcn_mfma_f32_16x16x32_bf16(ah[m], bl[step & 1][n], acc[m][n], 0, 0, 0);
            }
        }
    }
    __syncthreads();   // A reads done; sbuf becomes G (u32-packed hi/lo)

    // --- LN-folded gate, all lanes active ---
    const int j = l & 15;
    const int e0 = (j >= 8) ? 2 : 0;
#pragma unroll
    for (int m = 0; m < 4; ++m) {
#pragma unroll
        for (int n = 0; n < 4; ++n) {
            const f32x4 a = acc[m][n];
            float pr[4];
#pragma unroll
            for (int e = 0; e < 4; ++e) pr[e] = __shfl_xor(a[e], 8);
            const int cl = (w >> 1)*32 + n*8 + (j & 7);
            const int och = o0 + cl;
            const float c1p = cb[och],       c2p = cb[128 + och];
            const float c1g = cb[256 + och], c2g = cb[384 + och];
            const int p0 = mrow + m*16 + (l >> 4)*4;
            uint2 pk;
#pragma unroll
            for (int t = 0; t < 2; ++t) {
                const int e = e0 + t;
                const float accP = (j >= 8) ? pr[e] : a[e];
                const float accG = (j >= 8) ? a[e] : pr[e];
                const float mu = Mu[p0+e], rstd = Rs[p0+e];
                const float p_ = fmaf(rstd, accP - mu*c1p, c2p);
                const float g_ = fmaf(rstd, accG - mu*c1g, c2g);
                const float gv = p_ * sigmoidf_(g_) * Ms[p0+e];
                const ushort hi = bfbits(gv);
                const ushort lo = bfbits(gv - bf2f(hi));
                ((uint32*)&pk)[t] = ((uint32)hi << 16) | (uint32)lo;
            }
            *(uint2*)(sbuf + cl*512 + ((p0*4) ^ ((cl & 7) << 4)) + e0*4) = pk;
        }
    }
    __syncthreads();

    // --- cooperative plane stores: 256B-contiguous runs per plane ---
#pragma unroll
    for (int it = 0; it < 2; ++it) {
        const int u = it*256 + tid;
        const int c = u >> 3, seg = u & 7;
        ushort* hd = wsg + (long)(o0 + c) * NN + outBase + seg*16;
        ushort* ld = wsg + (long)(128 + o0 + c) * NN + outBase + seg*16;
#pragma unroll
        for (int half = 0; half < 2; ++half) {
            short8 hv, lv;
#pragma unroll
            for (int q = 0; q < 2; ++q) {
                const int b = seg*64 + half*32 + q*16;
                const uint4 w4 = *(const uint4*)(sbuf + c*512 + (b ^ ((c & 7) << 4)));
                hv[q*4+0] = (short)(w4.x >> 16); lv[q*4+0] = (short)(w4.x & 0xffffu);
                hv[q*4+1] = (short)(w4.y >> 16); lv[q*4+1] = (short)(w4.y & 0xffffu);
                hv[q*4+2] = (short)(w4.z >> 16); lv[q*4+2] = (short)(w4.z & 0xffffu);
                hv[q*4+3] = (short)(w4.w >> 16); lv[q*4+3] = (short)(w4.w & 0xffffu);
            }
            *(short8*)(hd + half*8) = hv;
            *(short8*)(ld + half*8) = lv;
        }
    }
}

// ---------------------------------------------------------------------------
// Triangular einsums: 256x256 tile, 8 waves, BK=32, dbuf, hi/lo 3-product.
// Output t stored as bf16.
// ---------------------------------------------------------------------------
__global__ __launch_bounds__(512, 1)
void k_einsum(const ushort* __restrict__ wsg, ushort* __restrict__ wst)
{
    const int bid = blockIdx.x;                  // 0..255
    const int nb  = (bid & 7) * 32 + (bid >> 3);
    const int ch  = nb >> 2;
    const int bi  = (nb >> 1) & 1, bj = nb & 1;
    const int pch = (ch < 32) ? ch : ch + 32;

    const ushort* __restrict__ PH = wsg + (long)pch * NN;
    const ushort* __restrict__ QH = wsg + (long)(pch + 32) * NN;
    ushort* __restrict__ T = wst + (long)ch * NN;

    __shared__ char smem[131072];

    const int tid = threadIdx.x;
    const int w = tid >> 6, l = tid & 63;
    const int isB = w >> 2;

    const ushort* sbase = isB ? (QH + (long)bj * 131072) : (PH + (long)bi * 131072);
    int soff[8];
#pragma unroll
    for (int i = 0; i < 8; ++i) {
        const int ci  = ((w & 3) * 8 + i) * 64 + l;
        const int row = ci >> 3, s = ci & 7;
        const int c   = s ^ (row & 7);
        soff[i] = row * 512 + (c >> 2) * (128 * NN) + (c & 3) * 8;
    }
    const int dbase = isB * 32768 + (w & 3) * 8192;

    f32x4 acc[4][8];
#pragma unroll
    for (int m = 0; m < 4; ++m)
#pragma unroll
        for (int n = 0; n < 8; ++n) acc[m][n] = (f32x4){0.f, 0.f, 0.f, 0.f};

    const int wr = w >> 1;
    const int wc = w & 1;

#define STAGE(buf, step)                                                           \
    {                                                                              \
        const int kOff = (step) * 32;                                              \
        _Pragma("unroll")                                                          \
        for (int i = 0; i < 8; ++i) {                                              \
            __builtin_amdgcn_global_load_lds(                                      \
                (const __attribute__((address_space(1))) void*)(sbase + soff[i] + kOff), \
                (__attribute__((address_space(3))) void*)(smem + (buf)*65536 + dbase + i*1024), \
                16, 0, 0);                                                         \
        }                                                                          \
    }

    STAGE(0, 0);
    __syncthreads();

    for (int t = 0; t < 16; ++t) {
        const int cur = t & 1;
        if (t < 15) STAGE(cur ^ 1, t + 1);

        const char* sA = (const char*)smem + cur * 65536;
        const char* sB = sA + 32768;
        const int jc = l >> 4;
        short8 ah[4], al[4];
#pragma unroll
        for (int m = 0; m < 4; ++m) {
            const int r = wr * 64 + m * 16 + (l & 15);
            ah[m] = *(const short8*)(sA + r * 128 + ((jc       ^ (r & 7)) << 4));
            al[m] = *(const short8*)(sA + r * 128 + (((jc | 4) ^ (r & 7)) << 4));
        }
#pragma unroll
        for (int n = 0; n < 8; ++n) {
            const int r = wc * 128 + n * 16 + (l & 15);
            const short8 bh = *(const short8*)(sB + r * 128 + ((jc       ^ (r & 7)) << 4));
            const short8 bl = *(const short8*)(sB + r * 128 + (((jc | 4) ^ (r & 7)) << 4));
#pragma unroll
            for (int m = 0; m < 4; ++m) {
                acc[m][n] = __builtin_amdgcn_mfma_f32_16x16x32_bf16(ah[m], bh, acc[m][n], 0, 0, 0);
                acc[m][n] = __builtin_amdgcn_mfma_f32_16x16x32_bf16(ah[m], bl, acc[m][n], 0, 0, 0);
                acc[m][n] = __builtin_amdgcn_mfma_f32_16x16x32_bf16(al[m], bh, acc[m][n], 0, 0, 0);
            }
        }
        __syncthreads();
    }
#undef STAGE

    const int rbase = bi * 256 + wr * 64;
    const int cbase = bj * 256 + wc * 128;
#pragma unroll
    for (int m = 0; m < 4; ++m) {
#pragma unroll
        for (int n = 0; n < 8; ++n) {
#pragma unroll
            for (int r = 0; r < 4; ++r) {
                const int row = rbase + m * 16 + (l >> 4) * 4 + r;
                const int col = cbase + n * 16 + (l & 15);
                T[(long)row * NDIM + col] = bfbits(acc[m][n][r]);
            }
        }
    }
}

// ---------------------------------------------------------------------------
// Stage 2 MERGED: 64-position blocks, ALL 128 output channels per block.
// One t-gather + one stats pass; fully contiguous 512B output rows.
// ---------------------------------------------------------------------------
__global__ __launch_bounds__(256, 3)
void k_stage2(const ushort* __restrict__ wst, const float* __restrict__ mask,
              const ushort* __restrict__ wt2, const float* __restrict__ cb,
              float* __restrict__ out)
{
    __shared__ char buf[33792];    // A [64 pos][64 ch] bf16 swz (8K); then O fp32 [64][132]
    __shared__ float Ms[64], Mu[64], Rs[64];

    const int tid = threadIdx.x;
    const long pos0 = (long)blockIdx.x * 64;
    const int w = tid >> 6, l = tid & 63;
    const int mrow = (w & 1) * 32;       // 2 m-frags
    const int ncol = (w >> 1) * 128;     // 8 n-frags over 256 B-rows

    // gather: plane d, 8 positions -> scatter into swizzled A tile
#pragma unroll
    for (int q = 0; q < 2; ++q) {
        const int u = q*256 + tid, d = u >> 3, p8 = (u & 7) * 8;
        const short8 v = *(const short8*)(wst + (long)d * NN + pos0 + p8);
#pragma unroll
        for (int e = 0; e < 8; ++e) {
            const int row = p8 + e;
            *(ushort*)(buf + row*128 + ((d*2) ^ ((row & 7) << 4))) = v[e];
        }
    }
    if (tid < 64) Ms[tid] = mask[pos0 + tid];
    __syncthreads();

    // LN2 stats
    {
        const int r = tid >> 2, qf = tid & 3;
        float s = 0.f, ss = 0.f;
#pragma unroll
        for (int c = 0; c < 2; ++c) {
            const short8 hv = *(const short8*)(buf + r*128 + ((qf*32 + c*16) ^ ((r & 7) << 4)));
#pragma unroll
            for (int e = 0; e < 8; ++e) {
                const float tv = bf2f((ushort)hv[e]);
                s += tv; ss = fmaf(tv, tv, ss);
            }
        }
        s  += __shfl_xor(s, 1);  s  += __shfl_xor(s, 2);
        ss += __shfl_xor(ss, 1); ss += __shfl_xor(ss, 2);
        const float mu = s * (1.f/64.f);
        const float var = ss * (1.f/64.f) - mu*mu;
        const float rstd = rsqrtf(var + 1e-5f);
        if (qf == 0) { Mu[r] = mu; Rs[r] = rstd; }
    }
    __syncthreads();

    f32x4 acc[2][8];
#pragma unroll
    for (int m = 0; m < 2; ++m)
#pragma unroll
        for (int n = 0; n < 8; ++n) acc[m][n] = (f32x4){0.f,0.f,0.f,0.f};

#pragma unroll
    for (int step = 0; step < 2; ++step) {
        short8 ah[2];
#pragma unroll
        for (int m = 0; m < 2; ++m) {
            const int pos = mrow + m*16 + (l & 15);
            const int col = (step*64 + (l >> 4)*16) ^ ((pos & 7) << 4);
            ah[m] = *(const short8*)(buf + pos*128 + col);
        }
#pragma unroll
        for (int n = 0; n < 8; ++n) {
            const int row = ncol + n*16 + (l & 15);
            const int idx = row*64 + step*32 + (l >> 4)*8;
            const short8 bh = *(const short8*)(wt2 + idx);
            const short8 bl = *(const short8*)(wt2 + 16384 + idx);
#pragma unroll
            for (int m = 0; m < 2; ++m) {
                acc[m][n] = __builtin_amdgcn_mfma_f32_16x16x32_bf16(ah[m], bh, acc[m][n], 0, 0, 0);
                acc[m][n] = __builtin_amdgcn_mfma_f32_16x16x32_bf16(ah[m], bl, acc[m][n], 0, 0, 0);
            }
        }
    }
    __syncthreads();   // A reads done; buf becomes O [64][132] fp32

    // LN-folded gate, all lanes active; O[pos][ch]
    const int j = l & 15;
    const int e0 = (j >= 8) ? 2 : 0;
#pragma unroll
    for (int m = 0; m < 2; ++m) {
#pragma unroll
        for (int n = 0; n < 8; ++n) {
            const f32x4 a = acc[m][n];
            float pr[4];
#pragma unroll
            for (int e = 0; e < 4; ++e) pr[e] = __shfl_xor(a[e], 8);
            const int och = ((w >> 1)*8 + n)*8 + (j & 7);   // global channel 0..127
            const float c1p = cb[och],       c2p = cb[128 + och];
            const float c1g = cb[256 + och], c2g = cb[384 + och];
            const int p0 = mrow + m*16 + (l >> 4)*4;
#pragma unroll
            for (int t = 0; t < 2; ++t) {
                const int e = e0 + t;
                const float accP = (j >= 8) ? pr[e] : a[e];
                const float accG = (j >= 8) ? a[e] : pr[e];
                const float mu = Mu[p0+e], rstd = Rs[p0+e];
                const float p_ = fmaf(rstd, accP - mu*c1p, c2p);
                const float g_ = fmaf(rstd, accG - mu*c1g, c2g);
                *(float*)(buf + (p0+e)*528 + och*4) = p_ * sigmoidf_(g_) * Ms[p0+e];
            }
        }
    }
    __syncthreads();

    // contiguous output stores: 512B per row, 4 threads/row x 8 float4
    {
        const int r2 = tid >> 2, h2 = tid & 3;
        float* op = out + (pos0 + r2)*128 + h2*32;
#pragma unroll
        for (int i = 0; i < 8; ++i)
            *(float4*)(op + i*4) = *(const float4*)(buf + r2*528 + (h2*32 + i*4)*4);
    }
}

// ---------------------------------------------------------------------------
extern "C" void kernel_launch(void* const* d_in, const int* in_sizes, int n_in,
                              void* d_out, int out_size, void* d_ws, size_t ws_size,
                              hipStream_t stream)
{
    const float* x     = (const float*)d_in[0];
    const float* mask  = (const float*)d_in[1];
    const float* ln1_w = (const float*)d_in[2];
    const float* ln1_b = (const float*)d_in[3];
    const float* pi_w  = (const float*)d_in[4];
    const float* pi_b  = (const float*)d_in[5];
    const float* gi_w  = (const float*)d_in[6];
    const float* gi_b  = (const float*)d_in[7];
    const float* ln2_w = (const float*)d_in[8];
    const float* ln2_b = (const float*)d_in[9];
    const float* po_w  = (const float*)d_in[10];
    const float* po_b  = (const float*)d_in[11];
    const float* go_w  = (const float*)d_in[12];
    const float* go_b  = (const float*)d_in[13];

    ushort* wsg  = (ushort*)d_ws;                               // 256 bf16 g planes
    ushort* wstu = (ushort*)((char*)d_ws + (long)256 * NN * 2); // 64 bf16 t planes
    ushort* wt1  = wstu;                                        // transient (pre-einsum)
    float*  cb1  = (float*)(wt1 + 65536);
    ushort* wt2  = wsg;                                         // transient (post-einsum)
    float*  cb2  = (float*)(wt2 + 32768);

    k_prep<<<66, 256, 0, stream>>>(pi_w, gi_w, ln1_w, ln1_b, pi_b, gi_b, 128, wt1, cb1);
    k_stage1<<<4096, 256, 0, stream>>>(x, mask, wt1, cb1, wsg);
    k_einsum<<<256, 512, 0, stream>>>(wsg, wstu);
    k_prep<<<34, 256, 0, stream>>>(po_w, go_w, ln2_w, ln2_b, po_b, go_b, 64, wt2, cb2);
    k_stage2<<<4096, 256, 0, stream>>>(wstu, mask, wt2, cb2, (float*)d_out);
}

// Round 14
// 337.962 us; speedup vs baseline: 1.2174x; 1.0641x over previous
//
#include <hip/hip_runtime.h>
#include <hip/hip_bf16.h>

#define NDIM 512
#define NN   (NDIM * NDIM)

// Workspace:
//   bf16 planes 0..127   : g hi, channel c.  c<64: [i][k]=g[i][k][c]; c>=64: [i][k]=g[k][i][c]
//   bf16 planes 128..255 : g lo, same indexing.              (128 MiB)
//   bf16 t planes @ 256*NN*2 B: t[dd][i][j], 64 planes        (32 MiB)
// Transient: wt1+cb1 at t-plane start; wt2+cb2 at wsg start (post-einsum).
// LN folded into GEMMs: out = rstd*(acc - mu*c1) + c2, W' = ln_w*W.

using short8 = __attribute__((ext_vector_type(8))) short;
using f32x4  = __attribute__((ext_vector_type(4))) float;
typedef unsigned int uint32;
typedef unsigned short ushort;

__device__ __forceinline__ float sigmoidf_(float z) { return 1.f / (1.f + __expf(-z)); }
__device__ __forceinline__ uint32 pkbf2(float a, float b) {
    __hip_bfloat162 h = __float22bfloat162_rn(float2{a, b});
    uint32 u; __builtin_memcpy(&u, &h, 4); return u;
}
__device__ __forceinline__ ushort bfbits(float f) {
    __hip_bfloat16 h = __float2bfloat16(f);
    ushort u; __builtin_memcpy(&u, &h, 2); return u;
}
__device__ __forceinline__ float bf2f(ushort h) {
    return __uint_as_float(((uint32)h) << 16);
}

// ---------------------------------------------------------------------------
// Weight prep + csum merged.
// ---------------------------------------------------------------------------
__global__ void k_prep(const float* __restrict__ Wp, const float* __restrict__ Wg,
                       const float* __restrict__ lnw, const float* __restrict__ lnb,
                       const float* __restrict__ bp, const float* __restrict__ bg,
                       int K, ushort* __restrict__ dst, float* __restrict__ cb)
{
    __shared__ float red[2][2][128];
    const int nbp = (K * 128) / 256;
    const int tid = threadIdx.x;
    if ((int)blockIdx.x < nbp) {
        const int idx = blockIdx.x * 256 + tid;
        const int k = idx >> 7, o = idx & 127;
        const int h = o >> 6, cl = o & 63;
        const int q = cl >> 3, s7 = cl & 7;
        const float wk = lnw[k];
        const float vp = Wp[k * 128 + o] * wk;
        const float vg = Wg[k * 128 + o] * wk;
        const int rowp = (q << 4) + s7;
        const int rowg = (q << 4) + 8 + s7;
        ushort hi;
        hi = bfbits(vp);
        dst[(h * 128 + rowp) * K + k] = hi;
        dst[256 * K + (h * 128 + rowp) * K + k] = bfbits(vp - bf2f(hi));
        hi = bfbits(vg);
        dst[(h * 128 + rowg) * K + k] = hi;
        dst[256 * K + (h * 128 + rowg) * K + k] = bfbits(vg - bf2f(hi));
    } else {
        const int b = blockIdx.x - nbp;
        const float* W = b ? Wg : Wp;
        const float* bias = b ? bg : bp;
        const int o = tid & 127, kh = tid >> 7;
        const int kham = K >> 1;
        const int k0 = kh * kham;
        float c1 = 0.f, c2 = 0.f;
#pragma unroll 8
        for (int k = 0; k < kham; ++k) {
            const float wv = W[(k0 + k) * 128 + o];
            c1 = fmaf(lnw[k0 + k], wv, c1);
            c2 = fmaf(lnb[k0 + k], wv, c2);
        }
        red[kh][0][o] = c1; red[kh][1][o] = c2;
        __syncthreads();
        if (kh == 0) {
            const int base = b ? 256 : 0;
            cb[base + o] = red[0][0][o] + red[1][0][o];
            cb[base + 128 + o] = red[0][1][o] + red[1][1][o] + bias[o];
        }
    }
}

// ---------------------------------------------------------------------------
// Stage 1 (unchanged from r13): 128-position blocks, twin-paired 1D grid.
// ---------------------------------------------------------------------------
__global__ __launch_bounds__(256, 4)
void k_stage1(const float* __restrict__ x, const float* __restrict__ mask,
              const ushort* __restrict__ wt1, const float* __restrict__ cb,
              ushort* __restrict__ wsg)
{
    __shared__ char sbuf[32768];   // A tile bf16(x) swz; later G u32-packed
    __shared__ float Ms[128], Mu[128], Rs[128];

    const int tid = threadIdx.x;
    const int g  = blockIdx.x;
    const int y  = (g >> 3) & 1;
    const int bx = (g & 7) | ((g >> 4) << 3);
    const int o0 = y * 64;
    const int w = tid >> 6, l = tid & 63;
    const int mrow = (w & 1) * 64, ncol = (w >> 1) * 64;

    long posBase, outBase; int stride;
    if (y == 0) {
        posBase = ((long)(bx >> 2)) * 512 + (long)(bx & 3) * 128;
        outBase = posBase; stride = 1;
    } else {
        posBase = ((long)(bx >> 9)) * 65536 + (bx & 511);
        outBase = (long)(bx & 511) * 512 + ((bx >> 9) * 128);
        stride = 512;
    }

    // --- B prefetch for step 0 (overlaps x-load/LN) ---
    short8 bh[2][4], bl[2][4];
#pragma unroll
    for (int n = 0; n < 4; ++n) {
        const int row = y*128 + ncol + n*16 + (l & 15);
        const int idx = row*128 + (l >> 4)*8;
        bh[0][n] = *(const short8*)(wt1 + idx);
        bl[0][n] = *(const short8*)(wt1 + 32768 + idx);
    }

    // --- load x, cast to bf16 A tile, one-pass stats ---
    {
        const int r = tid >> 1, hf = tid & 1;
        const float* xr = x + (posBase + (long)r * stride) * 128 + hf * 64;
        float s = 0.f, ss = 0.f;
#pragma unroll
        for (int q = 0; q < 8; ++q) {
            const float4 a = ((const float4*)xr)[2*q];
            const float4 b = ((const float4*)xr)[2*q+1];
            s  += a.x + a.y + a.z + a.w + b.x + b.y + b.z + b.w;
            ss = fmaf(a.x,a.x, fmaf(a.y,a.y, fmaf(a.z,a.z, fmaf(a.w,a.w, ss))));
            ss = fmaf(b.x,b.x, fmaf(b.y,b.y, fmaf(b.z,b.z, fmaf(b.w,b.w, ss))));
            uint4 pk;
            pk.x = pkbf2(a.x, a.y); pk.y = pkbf2(a.z, a.w);
            pk.z = pkbf2(b.x, b.y); pk.w = pkbf2(b.z, b.w);
            const int col = (hf*128 + q*16) ^ ((r & 15) << 4);
            *(uint4*)(sbuf + r*256 + col) = pk;
        }
        s  += __shfl_xor(s, 1);
        ss += __shfl_xor(ss, 1);
        const float mu = s * (1.f/128.f);
        const float var = ss * (1.f/128.f) - mu*mu;
        const float rstd = rsqrtf(var + 1e-5f);
        if (hf == 0) {
            Ms[r] = mask[posBase + (long)r * stride];
            Mu[r] = mu; Rs[r] = rstd;
        }
    }
    __syncthreads();

    f32x4 acc[4][4];
#pragma unroll
    for (int m = 0; m < 4; ++m)
#pragma unroll
        for (int n = 0; n < 4; ++n) acc[m][n] = (f32x4){0.f,0.f,0.f,0.f};

#pragma unroll
    for (int step = 0; step < 4; ++step) {
        if (step < 3) {
            const int s1 = step + 1;
#pragma unroll
            for (int n = 0; n < 4; ++n) {
                const int row = y*128 + ncol + n*16 + (l & 15);
                const int idx = row*128 + s1*32 + (l >> 4)*8;
                bh[s1 & 1][n] = *(const short8*)(wt1 + idx);
                bl[s1 & 1][n] = *(const short8*)(wt1 + 32768 + idx);
            }
        }
        short8 ah[4];
#pragma unroll
        for (int m = 0; m < 4; ++m) {
            const int pos = mrow + m*16 + (l & 15);
            const int col = (step*64 + (l >> 4)*16) ^ ((pos & 15) << 4);
            ah[m] = *(const short8*)(sbuf + pos*256 + col);
        }
#pragma unroll
        for (int m = 0; m < 4; ++m) {
#pragma unroll
            for (int n = 0; n < 4; ++n) {
                acc[m][n] = __builtin_amdgcn_mfma_f32_16x16x32_bf16(ah[m], bh[step & 1][n], acc[m][n], 0, 0, 0);
                acc[m][n] = __builtin_amdgcn_mfma_f32_16x16x32_bf16(ah[m], bl[step & 1][n], acc[m][n], 0, 0, 0);
            }
        }
    }
    __syncthreads();   // A reads done; sbuf becomes G (u32-packed hi/lo)

    // --- LN-folded gate, all lanes active ---
    const int j = l & 15;
    const int e0 = (j >= 8) ? 2 : 0;
#pragma unroll
    for (int m = 0; m < 4; ++m) {
#pragma unroll
        for (int n = 0; n < 4; ++n) {
            const f32x4 a = acc[m][n];
            float pr[4];
#pragma unroll
            for (int e = 0; e < 4; ++e) pr[e] = __shfl_xor(a[e], 8);
            const int cl = (w >> 1)*32 + n*8 + (j & 7);
            const int och = o0 + cl;
            const float c1p = cb[och],       c2p = cb[128 + och];
            const float c1g = cb[256 + och], c2g = cb[384 + och];
            const int p0 = mrow + m*16 + (l >> 4)*4;
            uint2 pk;
#pragma unroll
            for (int t = 0; t < 2; ++t) {
                const int e = e0 + t;
                const float accP = (j >= 8) ? pr[e] : a[e];
                const float accG = (j >= 8) ? a[e] : pr[e];
                const float mu = Mu[p0+e], rstd = Rs[p0+e];
                const float p_ = fmaf(rstd, accP - mu*c1p, c2p);
                const float g_ = fmaf(rstd, accG - mu*c1g, c2g);
                const float gv = p_ * sigmoidf_(g_) * Ms[p0+e];
                const ushort hi = bfbits(gv);
                const ushort lo = bfbits(gv - bf2f(hi));
                ((uint32*)&pk)[t] = ((uint32)hi << 16) | (uint32)lo;
            }
            *(uint2*)(sbuf + cl*512 + ((p0*4) ^ ((cl & 7) << 4)) + e0*4) = pk;
        }
    }
    __syncthreads();

    // --- cooperative plane stores: 256B-contiguous runs per plane ---
#pragma unroll
    for (int it = 0; it < 2; ++it) {
        const int u = it*256 + tid;
        const int c = u >> 3, seg = u & 7;
        ushort* hd = wsg + (long)(o0 + c) * NN + outBase + seg*16;
        ushort* ld = wsg + (long)(128 + o0 + c) * NN + outBase + seg*16;
#pragma unroll
        for (int half = 0; half < 2; ++half) {
            short8 hv, lv;
#pragma unroll
            for (int q = 0; q < 2; ++q) {
                const int b = seg*64 + half*32 + q*16;
                const uint4 w4 = *(const uint4*)(sbuf + c*512 + (b ^ ((c & 7) << 4)));
                hv[q*4+0] = (short)(w4.x >> 16); lv[q*4+0] = (short)(w4.x & 0xffffu);
                hv[q*4+1] = (short)(w4.y >> 16); lv[q*4+1] = (short)(w4.y & 0xffffu);
                hv[q*4+2] = (short)(w4.z >> 16); lv[q*4+2] = (short)(w4.z & 0xffffu);
                hv[q*4+3] = (short)(w4.w >> 16); lv[q*4+3] = (short)(w4.w & 0xffffu);
            }
            *(short8*)(hd + half*8) = hv;
            *(short8*)(ld + half*8) = lv;
        }
    }
}

// ---------------------------------------------------------------------------
// Triangular einsums (unchanged): 256x256 tile, 8 waves, BK=32, dbuf,
// hi/lo 3-product, bf16 output.
// ---------------------------------------------------------------------------
__global__ __launch_bounds__(512, 1)
void k_einsum(const ushort* __restrict__ wsg, ushort* __restrict__ wst)
{
    const int bid = blockIdx.x;                  // 0..255
    const int nb  = (bid & 7) * 32 + (bid >> 3);
    const int ch  = nb >> 2;
    const int bi  = (nb >> 1) & 1, bj = nb & 1;
    const int pch = (ch < 32) ? ch : ch + 32;

    const ushort* __restrict__ PH = wsg + (long)pch * NN;
    const ushort* __restrict__ QH = wsg + (long)(pch + 32) * NN;
    ushort* __restrict__ T = wst + (long)ch * NN;

    __shared__ char smem[131072];

    const int tid = threadIdx.x;
    const int w = tid >> 6, l = tid & 63;
    const int isB = w >> 2;

    const ushort* sbase = isB ? (QH + (long)bj * 131072) : (PH + (long)bi * 131072);
    int soff[8];
#pragma unroll
    for (int i = 0; i < 8; ++i) {
        const int ci  = ((w & 3) * 8 + i) * 64 + l;
        const int row = ci >> 3, s = ci & 7;
        const int c   = s ^ (row & 7);
        soff[i] = row * 512 + (c >> 2) * (128 * NN) + (c & 3) * 8;
    }
    const int dbase = isB * 32768 + (w & 3) * 8192;

    f32x4 acc[4][8];
#pragma unroll
    for (int m = 0; m < 4; ++m)
#pragma unroll
        for (int n = 0; n < 8; ++n) acc[m][n] = (f32x4){0.f, 0.f, 0.f, 0.f};

    const int wr = w >> 1;
    const int wc = w & 1;

#define STAGE(buf, step)                                                           \
    {                                                                              \
        const int kOff = (step) * 32;                                              \
        _Pragma("unroll")                                                          \
        for (int i = 0; i < 8; ++i) {                                              \
            __builtin_amdgcn_global_load_lds(                                      \
                (const __attribute__((address_space(1))) void*)(sbase + soff[i] + kOff), \
                (__attribute__((address_space(3))) void*)(smem + (buf)*65536 + dbase + i*1024), \
                16, 0, 0);                                                         \
        }                                                                          \
    }

    STAGE(0, 0);
    __syncthreads();

    for (int t = 0; t < 16; ++t) {
        const int cur = t & 1;
        if (t < 15) STAGE(cur ^ 1, t + 1);

        const char* sA = (const char*)smem + cur * 65536;
        const char* sB = sA + 32768;
        const int jc = l >> 4;
        short8 ah[4], al[4];
#pragma unroll
        for (int m = 0; m < 4; ++m) {
            const int r = wr * 64 + m * 16 + (l & 15);
            ah[m] = *(const short8*)(sA + r * 128 + ((jc       ^ (r & 7)) << 4));
            al[m] = *(const short8*)(sA + r * 128 + (((jc | 4) ^ (r & 7)) << 4));
        }
#pragma unroll
        for (int n = 0; n < 8; ++n) {
            const int r = wc * 128 + n * 16 + (l & 15);
            const short8 bh = *(const short8*)(sB + r * 128 + ((jc       ^ (r & 7)) << 4));
            const short8 bl = *(const short8*)(sB + r * 128 + (((jc | 4) ^ (r & 7)) << 4));
#pragma unroll
            for (int m = 0; m < 4; ++m) {
                acc[m][n] = __builtin_amdgcn_mfma_f32_16x16x32_bf16(ah[m], bh, acc[m][n], 0, 0, 0);
                acc[m][n] = __builtin_amdgcn_mfma_f32_16x16x32_bf16(ah[m], bl, acc[m][n], 0, 0, 0);
                acc[m][n] = __builtin_amdgcn_mfma_f32_16x16x32_bf16(al[m], bh, acc[m][n], 0, 0, 0);
            }
        }
        __syncthreads();
    }
#undef STAGE

    const int rbase = bi * 256 + wr * 64;
    const int cbase = bj * 256 + wc * 128;
#pragma unroll
    for (int m = 0; m < 4; ++m) {
#pragma unroll
        for (int n = 0; n < 8; ++n) {
#pragma unroll
            for (int r = 0; r < 4; ++r) {
                const int row = rbase + m * 16 + (l >> 4) * 4 + r;
                const int col = cbase + n * 16 + (l & 15);
                T[(long)row * NDIM + col] = bfbits(acc[m][n][r]);
            }
        }
    }
}

// ---------------------------------------------------------------------------
// Stage 2: 64-position blocks, all 128 channels, DIRECT register stores
// (no O-LDS round-trip; L2 write-combining assembles full lines from the
// 32B-run sibling stores within the block).  LDS = 8.6KB -> occ 4.
// ---------------------------------------------------------------------------
__global__ __launch_bounds__(256, 4)
void k_stage2(const ushort* __restrict__ wst, const float* __restrict__ mask,
              const ushort* __restrict__ wt2, const float* __restrict__ cb,
              float* __restrict__ out)
{
    __shared__ char buf[8192];     // A [64 pos][64 ch] bf16 swz
    __shared__ float Ms[64], Mu[64], Rs[64];

    const int tid = threadIdx.x;
    const long pos0 = (long)blockIdx.x * 64;
    const int w = tid >> 6, l = tid & 63;
    const int mrow = (w & 1) * 32;       // 2 m-frags
    const int ncol = (w >> 1) * 128;     // 8 n-frags over 256 B-rows

    // gather: plane d, 8 positions -> scatter into swizzled A tile
#pragma unroll
    for (int q = 0; q < 2; ++q) {
        const int u = q*256 + tid, d = u >> 3, p8 = (u & 7) * 8;
        const short8 v = *(const short8*)(wst + (long)d * NN + pos0 + p8);
#pragma unroll
        for (int e = 0; e < 8; ++e) {
            const int row = p8 + e;
            *(ushort*)(buf + row*128 + ((d*2) ^ ((row & 7) << 4))) = v[e];
        }
    }
    if (tid < 64) Ms[tid] = mask[pos0 + tid];
    __syncthreads();

    // LN2 stats
    {
        const int r = tid >> 2, qf = tid & 3;
        float s = 0.f, ss = 0.f;
#pragma unroll
        for (int c = 0; c < 2; ++c) {
            const short8 hv = *(const short8*)(buf + r*128 + ((qf*32 + c*16) ^ ((r & 7) << 4)));
#pragma unroll
            for (int e = 0; e < 8; ++e) {
                const float tv = bf2f((ushort)hv[e]);
                s += tv; ss = fmaf(tv, tv, ss);
            }
        }
        s  += __shfl_xor(s, 1);  s  += __shfl_xor(s, 2);
        ss += __shfl_xor(ss, 1); ss += __shfl_xor(ss, 2);
        const float mu = s * (1.f/64.f);
        const float var = ss * (1.f/64.f) - mu*mu;
        const float rstd = rsqrtf(var + 1e-5f);
        if (qf == 0) { Mu[r] = mu; Rs[r] = rstd; }
    }
    __syncthreads();

    f32x4 acc[2][8];
#pragma unroll
    for (int m = 0; m < 2; ++m)
#pragma unroll
        for (int n = 0; n < 8; ++n) acc[m][n] = (f32x4){0.f,0.f,0.f,0.f};

#pragma unroll
    for (int step = 0; step < 2; ++step) {
        short8 ah[2];
#pragma unroll
        for (int m = 0; m < 2; ++m) {
            const int pos = mrow + m*16 + (l & 15);
            const int col = (step*64 + (l >> 4)*16) ^ ((pos & 7) << 4);
            ah[m] = *(const short8*)(buf + pos*128 + col);
        }
#pragma unroll
        for (int n = 0; n < 8; ++n) {
            const int row = ncol + n*16 + (l & 15);
            const int idx = row*64 + step*32 + (l >> 4)*8;
            const short8 bh = *(const short8*)(wt2 + idx);
            const short8 bl = *(const short8*)(wt2 + 16384 + idx);
#pragma unroll
            for (int m = 0; m < 2; ++m) {
                acc[m][n] = __builtin_amdgcn_mfma_f32_16x16x32_bf16(ah[m], bh, acc[m][n], 0, 0, 0);
                acc[m][n] = __builtin_amdgcn_mfma_f32_16x16x32_bf16(ah[m], bl, acc[m][n], 0, 0, 0);
            }
        }
    }

    // LN-folded gate, all lanes active; DIRECT stores to out
    const int j = l & 15;
    const int e0 = (j >= 8) ? 2 : 0;
#pragma unroll
    for (int m = 0; m < 2; ++m) {
#pragma unroll
        for (int n = 0; n < 8; ++n) {
            const f32x4 a = acc[m][n];
            float pr[4];
#pragma unroll
            for (int e = 0; e < 4; ++e) pr[e] = __shfl_xor(a[e], 8);
            const int och = ((w >> 1)*8 + n)*8 + (j & 7);   // global channel 0..127
            const float c1p = cb[och],       c2p = cb[128 + och];
            const float c1g = cb[256 + och], c2g = cb[384 + och];
            const int p0 = mrow + m*16 + (l >> 4)*4;
#pragma unroll
            for (int t = 0; t < 2; ++t) {
                const int e = e0 + t;
                const float accP = (j >= 8) ? pr[e] : a[e];
                const float accG = (j >= 8) ? a[e] : pr[e];
                const float mu = Mu[p0+e], rstd = Rs[p0+e];
                const float p_ = fmaf(rstd, accP - mu*c1p, c2p);
                const float g_ = fmaf(rstd, accG - mu*c1g, c2g);
                out[(pos0 + p0 + e)*128 + och] = p_ * sigmoidf_(g_) * Ms[p0+e];
            }
        }
    }
}

// ---------------------------------------------------------------------------
extern "C" void kernel_launch(void* const* d_in, const int* in_sizes, int n_in,
                              void* d_out, int out_size, void* d_ws, size_t ws_size,
                              hipStream_t stream)
{
    const float* x     = (const float*)d_in[0];
    const float* mask  = (const float*)d_in[1];
    const float* ln1_w = (const float*)d_in[2];
    const float* ln1_b = (const float*)d_in[3];
    const float* pi_w  = (const float*)d_in[4];
    const float* pi_b  = (const float*)d_in[5];
    const float* gi_w  = (const float*)d_in[6];
    const float* gi_b  = (const float*)d_in[7];
    const float* ln2_w = (const float*)d_in[8];
    const float* ln2_b = (const float*)d_in[9];
    const float* po_w  = (const float*)d_in[10];
    const float* po_b  = (const float*)d_in[11];
    const float* go_w  = (const float*)d_in[12];
    const float* go_b  = (const float*)d_in[13];

    ushort* wsg  = (ushort*)d_ws;                               // 256 bf16 g planes
    ushort* wstu = (ushort*)((char*)d_ws + (long)256 * NN * 2); // 64 bf16 t planes
    ushort* wt1  = wstu;                                        // transient (pre-einsum)
    float*  cb1  = (float*)(wt1 + 65536);
    ushort* wt2  = wsg;                                         // transient (post-einsum)
    float*  cb2  = (float*)(wt2 + 32768);

    k_prep<<<66, 256, 0, stream>>>(pi_w, gi_w, ln1_w, ln1_b, pi_b, gi_b, 128, wt1, cb1);
    k_stage1<<<4096, 256, 0, stream>>>(x, mask, wt1, cb1, wsg);
    k_einsum<<<256, 512, 0, stream>>>(wsg, wstu);
    k_prep<<<34, 256, 0, stream>>>(po_w, go_w, ln2_w, ln2_b, po_b, go_b, 64, wt2, cb2);
    k_stage2<<<4096, 256, 0, stream>>>(wstu, mask, wt2, cb2, (float*)d_out);
}

// Round 15
// 303.006 us; speedup vs baseline: 1.3579x; 1.1154x over previous
//
#include <hip/hip_runtime.h>
#include <hip/hip_bf16.h>

#define NDIM 512
#define NN   (NDIM * NDIM)

// Workspace:
//   bf16 planes 0..127 : g (single bf16), channel c.
//       c<64: [i][k]=g[i][k][c]; c>=64: [i][k]=g[k][i][c]    (64 MiB)
//   bf16 t planes @ 128*NN*2 B: t[dd][i][j], 64 planes        (32 MiB)
// Transient: wt1+cb1 at t-plane start; wt2+cb2 at wsg start (post-einsum).
// Weights stay hi/lo bf16 (accuracy); activations single bf16.
// LN folded into GEMMs: out = rstd*(acc - mu*c1) + c2, W' = ln_w*W.

using short8 = __attribute__((ext_vector_type(8))) short;
using f32x4  = __attribute__((ext_vector_type(4))) float;
typedef unsigned int uint32;
typedef unsigned short ushort;

__device__ __forceinline__ float sigmoidf_(float z) { return 1.f / (1.f + __expf(-z)); }
__device__ __forceinline__ uint32 pkbf2(float a, float b) {
    __hip_bfloat162 h = __float22bfloat162_rn(float2{a, b});
    uint32 u; __builtin_memcpy(&u, &h, 4); return u;
}
__device__ __forceinline__ ushort bfbits(float f) {
    __hip_bfloat16 h = __float2bfloat16(f);
    ushort u; __builtin_memcpy(&u, &h, 2); return u;
}
__device__ __forceinline__ float bf2f(ushort h) {
    return __uint_as_float(((uint32)h) << 16);
}

// ---------------------------------------------------------------------------
// Weight prep + csum merged (weights keep hi/lo).
// ---------------------------------------------------------------------------
__global__ void k_prep(const float* __restrict__ Wp, const float* __restrict__ Wg,
                       const float* __restrict__ lnw, const float* __restrict__ lnb,
                       const float* __restrict__ bp, const float* __restrict__ bg,
                       int K, ushort* __restrict__ dst, float* __restrict__ cb)
{
    __shared__ float red[2][2][128];
    const int nbp = (K * 128) / 256;
    const int tid = threadIdx.x;
    if ((int)blockIdx.x < nbp) {
        const int idx = blockIdx.x * 256 + tid;
        const int k = idx >> 7, o = idx & 127;
        const int h = o >> 6, cl = o & 63;
        const int q = cl >> 3, s7 = cl & 7;
        const float wk = lnw[k];
        const float vp = Wp[k * 128 + o] * wk;
        const float vg = Wg[k * 128 + o] * wk;
        const int rowp = (q << 4) + s7;
        const int rowg = (q << 4) + 8 + s7;
        ushort hi;
        hi = bfbits(vp);
        dst[(h * 128 + rowp) * K + k] = hi;
        dst[256 * K + (h * 128 + rowp) * K + k] = bfbits(vp - bf2f(hi));
        hi = bfbits(vg);
        dst[(h * 128 + rowg) * K + k] = hi;
        dst[256 * K + (h * 128 + rowg) * K + k] = bfbits(vg - bf2f(hi));
    } else {
        const int b = blockIdx.x - nbp;
        const float* W = b ? Wg : Wp;
        const float* bias = b ? bg : bp;
        const int o = tid & 127, kh = tid >> 7;
        const int kham = K >> 1;
        const int k0 = kh * kham;
        float c1 = 0.f, c2 = 0.f;
#pragma unroll 8
        for (int k = 0; k < kham; ++k) {
            const float wv = W[(k0 + k) * 128 + o];
            c1 = fmaf(lnw[k0 + k], wv, c1);
            c2 = fmaf(lnb[k0 + k], wv, c2);
        }
        red[kh][0][o] = c1; red[kh][1][o] = c2;
        __syncthreads();
        if (kh == 0) {
            const int base = b ? 256 : 0;
            cb[base + o] = red[0][0][o] + red[1][0][o];
            cb[base + 128 + o] = red[0][1][o] + red[1][1][o] + bias[o];
        }
    }
}

// ---------------------------------------------------------------------------
// Stage 1: 128-position blocks, twin-paired 1D grid; single-bf16 g output.
// ---------------------------------------------------------------------------
__global__ __launch_bounds__(256, 4)
void k_stage1(const float* __restrict__ x, const float* __restrict__ mask,
              const ushort* __restrict__ wt1, const float* __restrict__ cb,
              ushort* __restrict__ wsg)
{
    __shared__ char sbuf[32768];   // A tile bf16(x) swz; later G bf16 [64 ch][128 pos]
    __shared__ float Ms[128], Mu[128], Rs[128];

    const int tid = threadIdx.x;
    const int g  = blockIdx.x;
    const int y  = (g >> 3) & 1;
    const int bx = (g & 7) | ((g >> 4) << 3);
    const int o0 = y * 64;
    const int w = tid >> 6, l = tid & 63;
    const int mrow = (w & 1) * 64, ncol = (w >> 1) * 64;

    long posBase, outBase; int stride;
    if (y == 0) {
        posBase = ((long)(bx >> 2)) * 512 + (long)(bx & 3) * 128;
        outBase = posBase; stride = 1;
    } else {
        posBase = ((long)(bx >> 9)) * 65536 + (bx & 511);
        outBase = (long)(bx & 511) * 512 + ((bx >> 9) * 128);
        stride = 512;
    }

    // --- B prefetch for step 0 (overlaps x-load/LN) ---
    short8 bh[2][4], bl[2][4];
#pragma unroll
    for (int n = 0; n < 4; ++n) {
        const int row = y*128 + ncol + n*16 + (l & 15);
        const int idx = row*128 + (l >> 4)*8;
        bh[0][n] = *(const short8*)(wt1 + idx);
        bl[0][n] = *(const short8*)(wt1 + 32768 + idx);
    }

    // --- load x, cast to bf16 A tile, one-pass stats ---
    {
        const int r = tid >> 1, hf = tid & 1;
        const float* xr = x + (posBase + (long)r * stride) * 128 + hf * 64;
        float s = 0.f, ss = 0.f;
#pragma unroll
        for (int q = 0; q < 8; ++q) {
            const float4 a = ((const float4*)xr)[2*q];
            const float4 b = ((const float4*)xr)[2*q+1];
            s  += a.x + a.y + a.z + a.w + b.x + b.y + b.z + b.w;
            ss = fmaf(a.x,a.x, fmaf(a.y,a.y, fmaf(a.z,a.z, fmaf(a.w,a.w, ss))));
            ss = fmaf(b.x,b.x, fmaf(b.y,b.y, fmaf(b.z,b.z, fmaf(b.w,b.w, ss))));
            uint4 pk;
            pk.x = pkbf2(a.x, a.y); pk.y = pkbf2(a.z, a.w);
            pk.z = pkbf2(b.x, b.y); pk.w = pkbf2(b.z, b.w);
            const int col = (hf*128 + q*16) ^ ((r & 15) << 4);
            *(uint4*)(sbuf + r*256 + col) = pk;
        }
        s  += __shfl_xor(s, 1);
        ss += __shfl_xor(ss, 1);
        const float mu = s * (1.f/128.f);
        const float var = ss * (1.f/128.f) - mu*mu;
        const float rstd = rsqrtf(var + 1e-5f);
        if (hf == 0) {
            Ms[r] = mask[posBase + (long)r * stride];
            Mu[r] = mu; Rs[r] = rstd;
        }
    }
    __syncthreads();

    f32x4 acc[4][4];
#pragma unroll
    for (int m = 0; m < 4; ++m)
#pragma unroll
        for (int n = 0; n < 4; ++n) acc[m][n] = (f32x4){0.f,0.f,0.f,0.f};

#pragma unroll
    for (int step = 0; step < 4; ++step) {
        if (step < 3) {
            const int s1 = step + 1;
#pragma unroll
            for (int n = 0; n < 4; ++n) {
                const int row = y*128 + ncol + n*16 + (l & 15);
                const int idx = row*128 + s1*32 + (l >> 4)*8;
                bh[s1 & 1][n] = *(const short8*)(wt1 + idx);
                bl[s1 & 1][n] = *(const short8*)(wt1 + 32768 + idx);
            }
        }
        short8 ah[4];
#pragma unroll
        for (int m = 0; m < 4; ++m) {
            const int pos = mrow + m*16 + (l & 15);
            const int col = (step*64 + (l >> 4)*16) ^ ((pos & 15) << 4);
            ah[m] = *(const short8*)(sbuf + pos*256 + col);
        }
#pragma unroll
        for (int m = 0; m < 4; ++m) {
#pragma unroll
            for (int n = 0; n < 4; ++n) {
                acc[m][n] = __builtin_amdgcn_mfma_f32_16x16x32_bf16(ah[m], bh[step & 1][n], acc[m][n], 0, 0, 0);
                acc[m][n] = __builtin_amdgcn_mfma_f32_16x16x32_bf16(ah[m], bl[step & 1][n], acc[m][n], 0, 0, 0);
            }
        }
    }
    __syncthreads();   // A reads done; sbuf becomes G bf16 [64 ch][128 pos] swz

    // --- LN-folded gate, all lanes active; single-bf16 G ---
    const int j = l & 15;
    const int e0 = (j >= 8) ? 2 : 0;
#pragma unroll
    for (int m = 0; m < 4; ++m) {
#pragma unroll
        for (int n = 0; n < 4; ++n) {
            const f32x4 a = acc[m][n];
            float pr[4];
#pragma unroll
            for (int e = 0; e < 4; ++e) pr[e] = __shfl_xor(a[e], 8);
            const int cl = (w >> 1)*32 + n*8 + (j & 7);
            const int och = o0 + cl;
            const float c1p = cb[och],       c2p = cb[128 + och];
            const float c1g = cb[256 + och], c2g = cb[384 + och];
            const int p0 = mrow + m*16 + (l >> 4)*4;
            float gv[2];
#pragma unroll
            for (int t = 0; t < 2; ++t) {
                const int e = e0 + t;
                const float accP = (j >= 8) ? pr[e] : a[e];
                const float accG = (j >= 8) ? a[e] : pr[e];
                const float mu = Mu[p0+e], rstd = Rs[p0+e];
                const float p_ = fmaf(rstd, accP - mu*c1p, c2p);
                const float g_ = fmaf(rstd, accG - mu*c1g, c2g);
                gv[t] = p_ * sigmoidf_(g_) * Ms[p0+e];
            }
            const uint32 pk = pkbf2(gv[0], gv[1]);
            *(uint32*)(sbuf + cl*256 + (((p0 + e0)*2) ^ ((cl & 7) << 4))) = pk;
        }
    }
    __syncthreads();

    // --- cooperative plane stores: 256B-contiguous runs per plane ---
#pragma unroll
    for (int it = 0; it < 2; ++it) {
        const int u = it*256 + tid;
        const int c = u >> 3, seg = u & 7;            // 64 ch x 8 segs of 16 elems
        ushort* hd = wsg + (long)(o0 + c) * NN + outBase + seg*16;
#pragma unroll
        for (int q = 0; q < 2; ++q) {
            const short8 v = *(const short8*)(sbuf + c*256 + ((seg*32 + q*16) ^ ((c & 7) << 4)));
            *(short8*)(hd + q*8) = v;
        }
    }
}

// ---------------------------------------------------------------------------
// Triangular einsums: 256x256 tile, 8 waves, single-product bf16 MFMA.
// 2 buffers x (A 32K | B 32K), BK=64 per buffer, 8 k-iters.
// ---------------------------------------------------------------------------
__global__ __launch_bounds__(512, 1)
void k_einsum(const ushort* __restrict__ wsg, ushort* __restrict__ wst)
{
    const int bid = blockIdx.x;                  // 0..255
    const int nb  = (bid & 7) * 32 + (bid >> 3);
    const int ch  = nb >> 2;
    const int bi  = (nb >> 1) & 1, bj = nb & 1;
    const int pch = (ch < 32) ? ch : ch + 32;

    const ushort* __restrict__ PH = wsg + (long)pch * NN;
    const ushort* __restrict__ QH = wsg + (long)(pch + 32) * NN;
    ushort* __restrict__ T = wst + (long)ch * NN;

    __shared__ char smem[131072];   // 2 buf x (A 32K @0 | B 32K @32768)

    const int tid = threadIdx.x;
    const int w = tid >> 6, l = tid & 63;
    const int isB = w >> 2;

    // staging: 2048 16B-chunks per matrix per buffer = 256 rows x 8 chunks (k 0..63)
    const ushort* sbase = isB ? (QH + (long)bj * 131072) : (PH + (long)bi * 131072);
    int soff[8];
#pragma unroll
    for (int i = 0; i < 8; ++i) {
        const int ci  = ((w & 3) * 8 + i) * 64 + l;
        const int row = ci >> 3, s = ci & 7;
        const int c   = s ^ (row & 7);           // pre-swizzled k-chunk
        soff[i] = row * 512 + c * 8;
    }
    const int dbase = isB * 32768 + (w & 3) * 8192;

    f32x4 acc[4][8];
#pragma unroll
    for (int m = 0; m < 4; ++m)
#pragma unroll
        for (int n = 0; n < 8; ++n) acc[m][n] = (f32x4){0.f, 0.f, 0.f, 0.f};

    const int wr = w >> 1;
    const int wc = w & 1;

#define STAGE(buf, step)                                                           \
    {                                                                              \
        const int kOff = (step) * 64;                                              \
        _Pragma("unroll")                                                          \
        for (int i = 0; i < 8; ++i) {                                              \
            __builtin_amdgcn_global_load_lds(                                      \
                (const __attribute__((address_space(1))) void*)(sbase + soff[i] + kOff), \
                (__attribute__((address_space(3))) void*)(smem + (buf)*65536 + dbase + i*1024), \
                16, 0, 0);                                                         \
        }                                                                          \
    }

    STAGE(0, 0);
    __syncthreads();

    for (int t = 0; t < 8; ++t) {
        const int cur = t & 1;
        if (t < 7) STAGE(cur ^ 1, t + 1);

        const char* sA = (const char*)smem + cur * 65536;
        const char* sB = sA + 32768;
        const int jc = l >> 4;
        short8 ah[4][2];
#pragma unroll
        for (int m = 0; m < 4; ++m) {
            const int r = wr * 64 + m * 16 + (l & 15);
#pragma unroll
            for (int ks = 0; ks < 2; ++ks)
                ah[m][ks] = *(const short8*)(sA + r * 128 + ((((ks << 2) | jc) ^ (r & 7)) << 4));
        }
#pragma unroll
        for (int n = 0; n < 8; ++n) {
            const int r = wc * 128 + n * 16 + (l & 15);
            short8 bh0 = *(const short8*)(sB + r * 128 + (((0 | jc) ^ (r & 7)) << 4));
            short8 bh1 = *(const short8*)(sB + r * 128 + (((4 | jc) ^ (r & 7)) << 4));
#pragma unroll
            for (int m = 0; m < 4; ++m) {
                acc[m][n] = __builtin_amdgcn_mfma_f32_16x16x32_bf16(ah[m][0], bh0, acc[m][n], 0, 0, 0);
                acc[m][n] = __builtin_amdgcn_mfma_f32_16x16x32_bf16(ah[m][1], bh1, acc[m][n], 0, 0, 0);
            }
        }
        __syncthreads();
    }
#undef STAGE

    const int rbase = bi * 256 + wr * 64;
    const int cbase = bj * 256 + wc * 128;
#pragma unroll
    for (int m = 0; m < 4; ++m) {
#pragma unroll
        for (int n = 0; n < 8; ++n) {
#pragma unroll
            for (int r = 0; r < 4; ++r) {
                const int row = rbase + m * 16 + (l >> 4) * 4 + r;
                const int col = cbase + n * 16 + (l & 15);
                T[(long)row * NDIM + col] = bfbits(acc[m][n][r]);
            }
        }
    }
}

// ---------------------------------------------------------------------------
// Stage 2 (unchanged from r14): 64-position blocks, all 128 channels,
// direct register stores.
// ---------------------------------------------------------------------------
__global__ __launch_bounds__(256, 4)
void k_stage2(const ushort* __restrict__ wst, const float* __restrict__ mask,
              const ushort* __restrict__ wt2, const float* __restrict__ cb,
              float* __restrict__ out)
{
    __shared__ char buf[8192];     // A [64 pos][64 ch] bf16 swz
    __shared__ float Ms[64], Mu[64], Rs[64];

    const int tid = threadIdx.x;
    const long pos0 = (long)blockIdx.x * 64;
    const int w = tid >> 6, l = tid & 63;
    const int mrow = (w & 1) * 32;
    const int ncol = (w >> 1) * 128;

#pragma unroll
    for (int q = 0; q < 2; ++q) {
        const int u = q*256 + tid, d = u >> 3, p8 = (u & 7) * 8;
        const short8 v = *(const short8*)(wst + (long)d * NN + pos0 + p8);
#pragma unroll
        for (int e = 0; e < 8; ++e) {
            const int row = p8 + e;
            *(ushort*)(buf + row*128 + ((d*2) ^ ((row & 7) << 4))) = v[e];
        }
    }
    if (tid < 64) Ms[tid] = mask[pos0 + tid];
    __syncthreads();

    {
        const int r = tid >> 2, qf = tid & 3;
        float s = 0.f, ss = 0.f;
#pragma unroll
        for (int c = 0; c < 2; ++c) {
            const short8 hv = *(const short8*)(buf + r*128 + ((qf*32 + c*16) ^ ((r & 7) << 4)));
#pragma unroll
            for (int e = 0; e < 8; ++e) {
                const float tv = bf2f((ushort)hv[e]);
                s += tv; ss = fmaf(tv, tv, ss);
            }
        }
        s  += __shfl_xor(s, 1);  s  += __shfl_xor(s, 2);
        ss += __shfl_xor(ss, 1); ss += __shfl_xor(ss, 2);
        const float mu = s * (1.f/64.f);
        const float var = ss * (1.f/64.f) - mu*mu;
        const float rstd = rsqrtf(var + 1e-5f);
        if (qf == 0) { Mu[r] = mu; Rs[r] = rstd; }
    }
    __syncthreads();

    f32x4 acc[2][8];
#pragma unroll
    for (int m = 0; m < 2; ++m)
#pragma unroll
        for (int n = 0; n < 8; ++n) acc[m][n] = (f32x4){0.f,0.f,0.f,0.f};

#pragma unroll
    for (int step = 0; step < 2; ++step) {
        short8 ah[2];
#pragma unroll
        for (int m = 0; m < 2; ++m) {
            const int pos = mrow + m*16 + (l & 15);
            const int col = (step*64 + (l >> 4)*16) ^ ((pos & 7) << 4);
            ah[m] = *(const short8*)(buf + pos*128 + col);
        }
#pragma unroll
        for (int n = 0; n < 8; ++n) {
            const int row = ncol + n*16 + (l & 15);
            const int idx = row*64 + step*32 + (l >> 4)*8;
            const short8 bh = *(const short8*)(wt2 + idx);
            const short8 bl = *(const short8*)(wt2 + 16384 + idx);
#pragma unroll
            for (int m = 0; m < 2; ++m) {
                acc[m][n] = __builtin_amdgcn_mfma_f32_16x16x32_bf16(ah[m], bh, acc[m][n], 0, 0, 0);
                acc[m][n] = __builtin_amdgcn_mfma_f32_16x16x32_bf16(ah[m], bl, acc[m][n], 0, 0, 0);
            }
        }
    }

    const int j = l & 15;
    const int e0 = (j >= 8) ? 2 : 0;
#pragma unroll
    for (int m = 0; m < 2; ++m) {
#pragma unroll
        for (int n = 0; n < 8; ++n) {
            const f32x4 a = acc[m][n];
            float pr[4];
#pragma unroll
            for (int e = 0; e < 4; ++e) pr[e] = __shfl_xor(a[e], 8);
            const int och = ((w >> 1)*8 + n)*8 + (j & 7);
            const float c1p = cb[och],       c2p = cb[128 + och];
            const float c1g = cb[256 + och], c2g = cb[384 + och];
            const int p0 = mrow + m*16 + (l >> 4)*4;
#pragma unroll
            for (int t = 0; t < 2; ++t) {
                const int e = e0 + t;
                const float accP = (j >= 8) ? pr[e] : a[e];
                const float accG = (j >= 8) ? a[e] : pr[e];
                const float mu = Mu[p0+e], rstd = Rs[p0+e];
                const float p_ = fmaf(rstd, accP - mu*c1p, c2p);
                const float g_ = fmaf(rstd, accG - mu*c1g, c2g);
                out[(pos0 + p0 + e)*128 + och] = p_ * sigmoidf_(g_) * Ms[p0+e];
            }
        }
    }
}

// ---------------------------------------------------------------------------
extern "C" void kernel_launch(void* const* d_in, const int* in_sizes, int n_in,
                              void* d_out, int out_size, void* d_ws, size_t ws_size,
                              hipStream_t stream)
{
    const float* x     = (const float*)d_in[0];
    const float* mask  = (const float*)d_in[1];
    const float* ln1_w = (const float*)d_in[2];
    const float* ln1_b = (const float*)d_in[3];
    const float* pi_w  = (const float*)d_in[4];
    const float* pi_b  = (const float*)d_in[5];
    const float* gi_w  = (const float*)d_in[6];
    const float* gi_b  = (const float*)d_in[7];
    const float* ln2_w = (const float*)d_in[8];
    const float* ln2_b = (const float*)d_in[9];
    const float* po_w  = (const float*)d_in[10];
    const float* po_b  = (const float*)d_in[11];
    const float* go_w  = (const float*)d_in[12];
    const float* go_b  = (const float*)d_in[13];

    ushort* wsg  = (ushort*)d_ws;                               // 128 bf16 g planes (64 MiB)
    ushort* wstu = (ushort*)((char*)d_ws + (long)128 * NN * 2); // 64 bf16 t planes (32 MiB)
    ushort* wt1  = wstu;                                        // transient (pre-einsum)
    float*  cb1  = (float*)(wt1 + 65536);
    ushort* wt2  = wsg;                                         // transient (post-einsum)
    float*  cb2  = (float*)(wt2 + 32768);

    k_prep<<<66, 256, 0, stream>>>(pi_w, gi_w, ln1_w, ln1_b, pi_b, gi_b, 128, wt1, cb1);
    k_stage1<<<4096, 256, 0, stream>>>(x, mask, wt1, cb1, wsg);
    k_einsum<<<256, 512, 0, stream>>>(wsg, wstu);
    k_prep<<<34, 256, 0, stream>>>(po_w, go_w, ln2_w, ln2_b, po_b, go_b, 64, wt2, cb2);
    k_stage2<<<4096, 256, 0, stream>>>(wstu, mask, wt2, cb2, (float*)d_out);
}

// Round 16
// 270.123 us; speedup vs baseline: 1.5232x; 1.1217x over previous
//
#include <hip/hip_runtime.h>
#include <hip/hip_bf16.h>

#define NDIM 512
#define NN   (NDIM * NDIM)

// Workspace:
//   bf16 planes 0..127 : g (single bf16), channel c.
//       c<64: [i][k]=g[i][k][c]; c>=64: [i][k]=g[k][i][c]    (64 MiB)
//   bf16 t planes @ 128*NN*2 B: t[dd][i][j], 64 planes        (32 MiB)
// Transient: wt1+cb1 at t-plane start; wt2+cb2 at wsg start (post-einsum).
// Weights hi/lo bf16; activations single bf16.
// LN folded: out = rstd*(acc - mu*c1) + c2, W' = ln_w*W.
// W^T row layouts (pi/gi in SEPARATE fragment groups -> shuffle-free gate):
//   K=128 (stage1): ch o: h=o>>6,c=o&63,q=c>>5,s=c&31; pi row=h*128+q*64+s, gi row=+32.
//   K=64  (stage2): ch o: q=o>>6,s=o&63;               pi row=q*128+s,     gi row=+64.

using short8 = __attribute__((ext_vector_type(8))) short;
using f32x4  = __attribute__((ext_vector_type(4))) float;
typedef unsigned int uint32;
typedef unsigned short ushort;

__device__ __forceinline__ float sigmoidf_(float z) { return 1.f / (1.f + __expf(-z)); }
__device__ __forceinline__ uint32 pkbf2(float a, float b) {
    __hip_bfloat162 h = __float22bfloat162_rn(float2{a, b});
    uint32 u; __builtin_memcpy(&u, &h, 4); return u;
}
__device__ __forceinline__ ushort bfbits(float f) {
    __hip_bfloat16 h = __float2bfloat16(f);
    ushort u; __builtin_memcpy(&u, &h, 2); return u;
}
__device__ __forceinline__ float bf2f(ushort h) {
    return __uint_as_float(((uint32)h) << 16);
}

// ---------------------------------------------------------------------------
// Weight prep + csum merged (weights hi/lo; pi/gi in separate row groups).
// ---------------------------------------------------------------------------
__global__ void k_prep(const float* __restrict__ Wp, const float* __restrict__ Wg,
                       const float* __restrict__ lnw, const float* __restrict__ lnb,
                       const float* __restrict__ bp, const float* __restrict__ bg,
                       int K, ushort* __restrict__ dst, float* __restrict__ cb)
{
    __shared__ float red[2][2][128];
    const int nbp = (K * 128) / 256;
    const int tid = threadIdx.x;
    if ((int)blockIdx.x < nbp) {
        const int idx = blockIdx.x * 256 + tid;
        const int k = idx >> 7, o = idx & 127;
        int rowp, rowg;
        if (K == 128) {
            const int h = o >> 6, c = o & 63, q = c >> 5, s = c & 31;
            rowp = h * 128 + q * 64 + s;
            rowg = rowp + 32;
        } else {
            const int q = o >> 6, s = o & 63;
            rowp = q * 128 + s;
            rowg = rowp + 64;
        }
        const float wk = lnw[k];
        const float vp = Wp[k * 128 + o] * wk;
        const float vg = Wg[k * 128 + o] * wk;
        ushort hi;
        hi = bfbits(vp);
        dst[rowp * K + k] = hi;
        dst[256 * K + rowp * K + k] = bfbits(vp - bf2f(hi));
        hi = bfbits(vg);
        dst[rowg * K + k] = hi;
        dst[256 * K + rowg * K + k] = bfbits(vg - bf2f(hi));
    } else {
        const int b = blockIdx.x - nbp;
        const float* W = b ? Wg : Wp;
        const float* bias = b ? bg : bp;
        const int o = tid & 127, kh = tid >> 7;
        const int kham = K >> 1;
        const int k0 = kh * kham;
        float c1 = 0.f, c2 = 0.f;
#pragma unroll 8
        for (int k = 0; k < kham; ++k) {
            const float wv = W[(k0 + k) * 128 + o];
            c1 = fmaf(lnw[k0 + k], wv, c1);
            c2 = fmaf(lnb[k0 + k], wv, c2);
        }
        red[kh][0][o] = c1; red[kh][1][o] = c2;
        __syncthreads();
        if (kh == 0) {
            const int base = b ? 256 : 0;
            cb[base + o] = red[0][0][o] + red[1][0][o];
            cb[base + 128 + o] = red[0][1][o] + red[1][1][o] + bias[o];
        }
    }
}

// ---------------------------------------------------------------------------
// Stage 1: 128-position blocks, twin-paired 1D grid; single-bf16 g output.
// Gate is shuffle-free: acc[m][n] = pi, acc[m][n+2] = gi of SAME channel.
// ---------------------------------------------------------------------------
__global__ __launch_bounds__(256, 4)
void k_stage1(const float* __restrict__ x, const float* __restrict__ mask,
              const ushort* __restrict__ wt1, const float* __restrict__ cb,
              ushort* __restrict__ wsg)
{
    __shared__ char sbuf[32768];   // A tile bf16(x) swz; later G bf16 [64 ch][128 pos]
    __shared__ float Ms[128], Mu[128], Rs[128];

    const int tid = threadIdx.x;
    const int g  = blockIdx.x;
    const int y  = (g >> 3) & 1;
    const int bx = (g & 7) | ((g >> 4) << 3);
    const int o0 = y * 64;
    const int w = tid >> 6, l = tid & 63;
    const int mrow = (w & 1) * 64, ncol = (w >> 1) * 64;

    long posBase, outBase; int stride;
    if (y == 0) {
        posBase = ((long)(bx >> 2)) * 512 + (long)(bx & 3) * 128;
        outBase = posBase; stride = 1;
    } else {
        posBase = ((long)(bx >> 9)) * 65536 + (bx & 511);
        outBase = (long)(bx & 511) * 512 + ((bx >> 9) * 128);
        stride = 512;
    }

    // --- B prefetch for step 0 ---
    short8 bh[2][4], bl[2][4];
#pragma unroll
    for (int n = 0; n < 4; ++n) {
        const int row = y*128 + ncol + n*16 + (l & 15);
        const int idx = row*128 + (l >> 4)*8;
        bh[0][n] = *(const short8*)(wt1 + idx);
        bl[0][n] = *(const short8*)(wt1 + 32768 + idx);
    }

    // --- load x, cast to bf16 A tile, one-pass stats ---
    {
        const int r = tid >> 1, hf = tid & 1;
        const float* xr = x + (posBase + (long)r * stride) * 128 + hf * 64;
        float s = 0.f, ss = 0.f;
#pragma unroll
        for (int q = 0; q < 8; ++q) {
            const float4 a = ((const float4*)xr)[2*q];
            const float4 b = ((const float4*)xr)[2*q+1];
            s  += a.x + a.y + a.z + a.w + b.x + b.y + b.z + b.w;
            ss = fmaf(a.x,a.x, fmaf(a.y,a.y, fmaf(a.z,a.z, fmaf(a.w,a.w, ss))));
            ss = fmaf(b.x,b.x, fmaf(b.y,b.y, fmaf(b.z,b.z, fmaf(b.w,b.w, ss))));
            uint4 pk;
            pk.x = pkbf2(a.x, a.y); pk.y = pkbf2(a.z, a.w);
            pk.z = pkbf2(b.x, b.y); pk.w = pkbf2(b.z, b.w);
            const int col = (hf*128 + q*16) ^ ((r & 15) << 4);
            *(uint4*)(sbuf + r*256 + col) = pk;
        }
        s  += __shfl_xor(s, 1);
        ss += __shfl_xor(ss, 1);
        const float mu = s * (1.f/128.f);
        const float var = ss * (1.f/128.f) - mu*mu;
        const float rstd = rsqrtf(var + 1e-5f);
        if (hf == 0) {
            Ms[r] = mask[posBase + (long)r * stride];
            Mu[r] = mu; Rs[r] = rstd;
        }
    }
    __syncthreads();

    f32x4 acc[4][4];
#pragma unroll
    for (int m = 0; m < 4; ++m)
#pragma unroll
        for (int n = 0; n < 4; ++n) acc[m][n] = (f32x4){0.f,0.f,0.f,0.f};

#pragma unroll
    for (int step = 0; step < 4; ++step) {
        if (step < 3) {
            const int s1 = step + 1;
#pragma unroll
            for (int n = 0; n < 4; ++n) {
                const int row = y*128 + ncol + n*16 + (l & 15);
                const int idx = row*128 + s1*32 + (l >> 4)*8;
                bh[s1 & 1][n] = *(const short8*)(wt1 + idx);
                bl[s1 & 1][n] = *(const short8*)(wt1 + 32768 + idx);
            }
        }
        short8 ah[4];
#pragma unroll
        for (int m = 0; m < 4; ++m) {
            const int pos = mrow + m*16 + (l & 15);
            const int col = (step*64 + (l >> 4)*16) ^ ((pos & 15) << 4);
            ah[m] = *(const short8*)(sbuf + pos*256 + col);
        }
#pragma unroll
        for (int m = 0; m < 4; ++m) {
#pragma unroll
            for (int n = 0; n < 4; ++n) {
                acc[m][n] = __builtin_amdgcn_mfma_f32_16x16x32_bf16(ah[m], bh[step & 1][n], acc[m][n], 0, 0, 0);
                acc[m][n] = __builtin_amdgcn_mfma_f32_16x16x32_bf16(ah[m], bl[step & 1][n], acc[m][n], 0, 0, 0);
            }
        }
    }
    __syncthreads();   // A reads done; sbuf becomes G bf16 [64 ch][128 pos] swz

    // --- LN-folded gate: SHUFFLE-FREE (pi frag n, gi frag n+2, same lane) ---
#pragma unroll
    for (int m = 0; m < 4; ++m) {
#pragma unroll
        for (int n = 0; n < 2; ++n) {
            const f32x4 aP = acc[m][n];
            const f32x4 aG = acc[m][n + 2];
            const int cl = (w >> 1)*32 + n*16 + (l & 15);   // within-half channel
            const int och = o0 + cl;
            const float c1p = cb[och],       c2p = cb[128 + och];
            const float c1g = cb[256 + och], c2g = cb[384 + och];
            const int p0 = mrow + m*16 + (l >> 4)*4;
            float gv[4];
#pragma unroll
            for (int e = 0; e < 4; ++e) {
                const float mu = Mu[p0+e], rstd = Rs[p0+e];
                const float p_ = fmaf(rstd, aP[e] - mu*c1p, c2p);
                const float g_ = fmaf(rstd, aG[e] - mu*c1g, c2g);
                gv[e] = p_ * sigmoidf_(g_) * Ms[p0+e];
            }
            uint2 pk;
            pk.x = pkbf2(gv[0], gv[1]);
            pk.y = pkbf2(gv[2], gv[3]);
            *(uint2*)(sbuf + cl*256 + ((p0*2) ^ ((cl & 7) << 4))) = pk;
        }
    }
    __syncthreads();

    // --- cooperative plane stores: 256B-contiguous runs per plane ---
#pragma unroll
    for (int it = 0; it < 2; ++it) {
        const int u = it*256 + tid;
        const int c = u >> 3, seg = u & 7;
        ushort* hd = wsg + (long)(o0 + c) * NN + outBase + seg*16;
#pragma unroll
        for (int q = 0; q < 2; ++q) {
            const short8 v = *(const short8*)(sbuf + c*256 + ((seg*32 + q*16) ^ ((c & 7) << 4)));
            *(short8*)(hd + q*8) = v;
        }
    }
}

// ---------------------------------------------------------------------------
// Triangular einsums (unchanged): 256x256 tile, 8 waves, single-product,
// 2 buf x (A 32K | B 32K), BK=64/buffer, 8 k-iters, bf16 out.
// ---------------------------------------------------------------------------
__global__ __launch_bounds__(512, 1)
void k_einsum(const ushort* __restrict__ wsg, ushort* __restrict__ wst)
{
    const int bid = blockIdx.x;
    const int nb  = (bid & 7) * 32 + (bid >> 3);
    const int ch  = nb >> 2;
    const int bi  = (nb >> 1) & 1, bj = nb & 1;
    const int pch = (ch < 32) ? ch : ch + 32;

    const ushort* __restrict__ PH = wsg + (long)pch * NN;
    const ushort* __restrict__ QH = wsg + (long)(pch + 32) * NN;
    ushort* __restrict__ T = wst + (long)ch * NN;

    __shared__ char smem[131072];

    const int tid = threadIdx.x;
    const int w = tid >> 6, l = tid & 63;
    const int isB = w >> 2;

    const ushort* sbase = isB ? (QH + (long)bj * 131072) : (PH + (long)bi * 131072);
    int soff[8];
#pragma unroll
    for (int i = 0; i < 8; ++i) {
        const int ci  = ((w & 3) * 8 + i) * 64 + l;
        const int row = ci >> 3, s = ci & 7;
        const int c   = s ^ (row & 7);
        soff[i] = row * 512 + c * 8;
    }
    const int dbase = isB * 32768 + (w & 3) * 8192;

    f32x4 acc[4][8];
#pragma unroll
    for (int m = 0; m < 4; ++m)
#pragma unroll
        for (int n = 0; n < 8; ++n) acc[m][n] = (f32x4){0.f, 0.f, 0.f, 0.f};

    const int wr = w >> 1;
    const int wc = w & 1;

#define STAGE(buf, step)                                                           \
    {                                                                              \
        const int kOff = (step) * 64;                                              \
        _Pragma("unroll")                                                          \
        for (int i = 0; i < 8; ++i) {                                              \
            __builtin_amdgcn_global_load_lds(                                      \
                (const __attribute__((address_space(1))) void*)(sbase + soff[i] + kOff), \
                (__attribute__((address_space(3))) void*)(smem + (buf)*65536 + dbase + i*1024), \
                16, 0, 0);                                                         \
        }                                                                          \
    }

    STAGE(0, 0);
    __syncthreads();

    for (int t = 0; t < 8; ++t) {
        const int cur = t & 1;
        if (t < 7) STAGE(cur ^ 1, t + 1);

        const char* sA = (const char*)smem + cur * 65536;
        const char* sB = sA + 32768;
        const int jc = l >> 4;
        short8 ah[4][2];
#pragma unroll
        for (int m = 0; m < 4; ++m) {
            const int r = wr * 64 + m * 16 + (l & 15);
#pragma unroll
            for (int ks = 0; ks < 2; ++ks)
                ah[m][ks] = *(const short8*)(sA + r * 128 + ((((ks << 2) | jc) ^ (r & 7)) << 4));
        }
#pragma unroll
        for (int n = 0; n < 8; ++n) {
            const int r = wc * 128 + n * 16 + (l & 15);
            short8 bh0 = *(const short8*)(sB + r * 128 + (((0 | jc) ^ (r & 7)) << 4));
            short8 bh1 = *(const short8*)(sB + r * 128 + (((4 | jc) ^ (r & 7)) << 4));
#pragma unroll
            for (int m = 0; m < 4; ++m) {
                acc[m][n] = __builtin_amdgcn_mfma_f32_16x16x32_bf16(ah[m][0], bh0, acc[m][n], 0, 0, 0);
                acc[m][n] = __builtin_amdgcn_mfma_f32_16x16x32_bf16(ah[m][1], bh1, acc[m][n], 0, 0, 0);
            }
        }
        __syncthreads();
    }
#undef STAGE

    const int rbase = bi * 256 + wr * 64;
    const int cbase = bj * 256 + wc * 128;
#pragma unroll
    for (int m = 0; m < 4; ++m) {
#pragma unroll
        for (int n = 0; n < 8; ++n) {
#pragma unroll
            for (int r = 0; r < 4; ++r) {
                const int row = rbase + m * 16 + (l >> 4) * 4 + r;
                const int col = cbase + n * 16 + (l & 15);
                T[(long)row * NDIM + col] = bfbits(acc[m][n][r]);
            }
        }
    }
}

// ---------------------------------------------------------------------------
// Stage 2: 64-position blocks, all 128 channels, direct register stores.
// Gate shuffle-free: pi frag n (n<4), gi frag n+4, same lane.
// ---------------------------------------------------------------------------
__global__ __launch_bounds__(256, 4)
void k_stage2(const ushort* __restrict__ wst, const float* __restrict__ mask,
              const ushort* __restrict__ wt2, const float* __restrict__ cb,
              float* __restrict__ out)
{
    __shared__ char buf[8192];     // A [64 pos][64 ch] bf16 swz
    __shared__ float Ms[64], Mu[64], Rs[64];

    const int tid = threadIdx.x;
    const long pos0 = (long)blockIdx.x * 64;
    const int w = tid >> 6, l = tid & 63;
    const int mrow = (w & 1) * 32;
    const int ncol = (w >> 1) * 128;

#pragma unroll
    for (int q = 0; q < 2; ++q) {
        const int u = q*256 + tid, d = u >> 3, p8 = (u & 7) * 8;
        const short8 v = *(const short8*)(wst + (long)d * NN + pos0 + p8);
#pragma unroll
        for (int e = 0; e < 8; ++e) {
            const int row = p8 + e;
            *(ushort*)(buf + row*128 + ((d*2) ^ ((row & 7) << 4))) = v[e];
        }
    }
    if (tid < 64) Ms[tid] = mask[pos0 + tid];
    __syncthreads();

    {
        const int r = tid >> 2, qf = tid & 3;
        float s = 0.f, ss = 0.f;
#pragma unroll
        for (int c = 0; c < 2; ++c) {
            const short8 hv = *(const short8*)(buf + r*128 + ((qf*32 + c*16) ^ ((r & 7) << 4)));
#pragma unroll
            for (int e = 0; e < 8; ++e) {
                const float tv = bf2f((ushort)hv[e]);
                s += tv; ss = fmaf(tv, tv, ss);
            }
        }
        s  += __shfl_xor(s, 1);  s  += __shfl_xor(s, 2);
        ss += __shfl_xor(ss, 1); ss += __shfl_xor(ss, 2);
        const float mu = s * (1.f/64.f);
        const float var = ss * (1.f/64.f) - mu*mu;
        const float rstd = rsqrtf(var + 1e-5f);
        if (qf == 0) { Mu[r] = mu; Rs[r] = rstd; }
    }
    __syncthreads();

    f32x4 acc[2][8];
#pragma unroll
    for (int m = 0; m < 2; ++m)
#pragma unroll
        for (int n = 0; n < 8; ++n) acc[m][n] = (f32x4){0.f,0.f,0.f,0.f};

#pragma unroll
    for (int step = 0; step < 2; ++step) {
        short8 ah[2];
#pragma unroll
        for (int m = 0; m < 2; ++m) {
            const int pos = mrow + m*16 + (l & 15);
            const int col = (step*64 + (l >> 4)*16) ^ ((pos & 7) << 4);
            ah[m] = *(const short8*)(buf + pos*128 + col);
        }
#pragma unroll
        for (int n = 0; n < 8; ++n) {
            const int row = ncol + n*16 + (l & 15);
            const int idx = row*64 + step*32 + (l >> 4)*8;
            const short8 bh = *(const short8*)(wt2 + idx);
            const short8 bl = *(const short8*)(wt2 + 16384 + idx);
#pragma unroll
            for (int m = 0; m < 2; ++m) {
                acc[m][n] = __builtin_amdgcn_mfma_f32_16x16x32_bf16(ah[m], bh, acc[m][n], 0, 0, 0);
                acc[m][n] = __builtin_amdgcn_mfma_f32_16x16x32_bf16(ah[m], bl, acc[m][n], 0, 0, 0);
            }
        }
    }

    // --- LN-folded gate: shuffle-free (pi frag n, gi frag n+4) ---
#pragma unroll
    for (int m = 0; m < 2; ++m) {
#pragma unroll
        for (int n = 0; n < 4; ++n) {
            const f32x4 aP = acc[m][n];
            const f32x4 aG = acc[m][n + 4];
            const int och = (w >> 1)*64 + n*16 + (l & 15);   // global channel
            const float c1p = cb[och],       c2p = cb[128 + och];
            const float c1g = cb[256 + och], c2g = cb[384 + och];
            const int p0 = mrow + m*16 + (l >> 4)*4;
#pragma unroll
            for (int e = 0; e < 4; ++e) {
                const float mu = Mu[p0+e], rstd = Rs[p0+e];
                const float p_ = fmaf(rstd, aP[e] - mu*c1p, c2p);
                const float g_ = fmaf(rstd, aG[e] - mu*c1g, c2g);
                out[(pos0 + p0 + e)*128 + och] = p_ * sigmoidf_(g_) * Ms[p0+e];
            }
        }
    }
}

// ---------------------------------------------------------------------------
extern "C" void kernel_launch(void* const* d_in, const int* in_sizes, int n_in,
                              void* d_out, int out_size, void* d_ws, size_t ws_size,
                              hipStream_t stream)
{
    const float* x     = (const float*)d_in[0];
    const float* mask  = (const float*)d_in[1];
    const float* ln1_w = (const float*)d_in[2];
    const float* ln1_b = (const float*)d_in[3];
    const float* pi_w  = (const float*)d_in[4];
    const float* pi_b  = (const float*)d_in[5];
    const float* gi_w  = (const float*)d_in[6];
    const float* gi_b  = (const float*)d_in[7];
    const float* ln2_w = (const float*)d_in[8];
    const float* ln2_b = (const float*)d_in[9];
    const float* po_w  = (const float*)d_in[10];
    const float* po_b  = (const float*)d_in[11];
    const float* go_w  = (const float*)d_in[12];
    const float* go_b  = (const float*)d_in[13];

    ushort* wsg  = (ushort*)d_ws;                               // 128 bf16 g planes (64 MiB)
    ushort* wstu = (ushort*)((char*)d_ws + (long)128 * NN * 2); // 64 bf16 t planes (32 MiB)
    ushort* wt1  = wstu;                                        // transient (pre-einsum)
    float*  cb1  = (float*)(wt1 + 65536);
    ushort* wt2  = wsg;                                         // transient (post-einsum)
    float*  cb2  = (float*)(wt2 + 32768);

    k_prep<<<66, 256, 0, stream>>>(pi_w, gi_w, ln1_w, ln1_b, pi_b, gi_b, 128, wt1, cb1);
    k_stage1<<<4096, 256, 0, stream>>>(x, mask, wt1, cb1, wsg);
    k_einsum<<<256, 512, 0, stream>>>(wsg, wstu);
    k_prep<<<34, 256, 0, stream>>>(po_w, go_w, ln2_w, ln2_b, po_b, go_b, 64, wt2, cb2);
    k_stage2<<<4096, 256, 0, stream>>>(wstu, mask, wt2, cb2, (float*)d_out);
}

// Round 17
// 243.942 us; speedup vs baseline: 1.6867x; 1.1073x over previous
//
#include <hip/hip_runtime.h>
#include <hip/hip_bf16.h>

#define NDIM 512
#define NN   (NDIM * NDIM)

// Workspace:
//   bf16 planes 0..127 : g (single bf16), channel c.
//       c<64: [i][k]=g[i][k][c]; c>=64: [i][k]=g[k][i][c]    (64 MiB)
//   bf16 t planes @ 128*NN*2 B: t[dd][i][j], 64 planes        (32 MiB)
// Transient: wt1+cb1 at t-plane start; wt2+cb2 at wsg start (post-einsum).
// Weights hi/lo bf16; activations single bf16.
// LN folded: out = rstd*(acc - mu*c1) + c2, W' = ln_w*W.
// W^T row layouts (pi/gi separate fragment groups -> shuffle-free gate):
//   K=128: ch o: h=o>>6,c=o&63,q=c>>5,s=c&31; pi row=h*128+q*64+s, gi=+32.
//   K=64 : ch o: q=o>>6,s=o&63;               pi row=q*128+s,     gi=+64.

using short8 = __attribute__((ext_vector_type(8))) short;
using f32x4  = __attribute__((ext_vector_type(4))) float;
typedef unsigned int uint32;
typedef unsigned short ushort;

__device__ __forceinline__ float sigmoidf_(float z) { return 1.f / (1.f + __expf(-z)); }
__device__ __forceinline__ uint32 pkbf2(float a, float b) {
    __hip_bfloat162 h = __float22bfloat162_rn(float2{a, b});
    uint32 u; __builtin_memcpy(&u, &h, 4); return u;
}
__device__ __forceinline__ ushort bfbits(float f) {
    __hip_bfloat16 h = __float2bfloat16(f);
    ushort u; __builtin_memcpy(&u, &h, 2); return u;
}
__device__ __forceinline__ float bf2f(ushort h) {
    return __uint_as_float(((uint32)h) << 16);
}

// ---------------------------------------------------------------------------
// Weight prep + csum merged (weights hi/lo; pi/gi separate row groups).
// ---------------------------------------------------------------------------
__global__ void k_prep(const float* __restrict__ Wp, const float* __restrict__ Wg,
                       const float* __restrict__ lnw, const float* __restrict__ lnb,
                       const float* __restrict__ bp, const float* __restrict__ bg,
                       int K, ushort* __restrict__ dst, float* __restrict__ cb)
{
    __shared__ float red[2][2][128];
    const int nbp = (K * 128) / 256;
    const int tid = threadIdx.x;
    if ((int)blockIdx.x < nbp) {
        const int idx = blockIdx.x * 256 + tid;
        const int k = idx >> 7, o = idx & 127;
        int rowp, rowg;
        if (K == 128) {
            const int h = o >> 6, c = o & 63, q = c >> 5, s = c & 31;
            rowp = h * 128 + q * 64 + s;
            rowg = rowp + 32;
        } else {
            const int q = o >> 6, s = o & 63;
            rowp = q * 128 + s;
            rowg = rowp + 64;
        }
        const float wk = lnw[k];
        const float vp = Wp[k * 128 + o] * wk;
        const float vg = Wg[k * 128 + o] * wk;
        ushort hi;
        hi = bfbits(vp);
        dst[rowp * K + k] = hi;
        dst[256 * K + rowp * K + k] = bfbits(vp - bf2f(hi));
        hi = bfbits(vg);
        dst[rowg * K + k] = hi;
        dst[256 * K + rowg * K + k] = bfbits(vg - bf2f(hi));
    } else {
        const int b = blockIdx.x - nbp;
        const float* W = b ? Wg : Wp;
        const float* bias = b ? bg : bp;
        const int o = tid & 127, kh = tid >> 7;
        const int kham = K >> 1;
        const int k0 = kh * kham;
        float c1 = 0.f, c2 = 0.f;
#pragma unroll 8
        for (int k = 0; k < kham; ++k) {
            const float wv = W[(k0 + k) * 128 + o];
            c1 = fmaf(lnw[k0 + k], wv, c1);
            c2 = fmaf(lnb[k0 + k], wv, c2);
        }
        red[kh][0][o] = c1; red[kh][1][o] = c2;
        __syncthreads();
        if (kh == 0) {
            const int base = b ? 256 : 0;
            cb[base + o] = red[0][0][o] + red[1][0][o];
            cb[base + 128 + o] = red[0][1][o] + red[1][1][o] + bias[o];
        }
    }
}

// ---------------------------------------------------------------------------
// Stage 1: 128-position blocks, twin-paired 1D grid; single-bf16 g output.
// NEW: lane-linear coalesced x loads (stats decoupled — computed from the
// LDS tile after the barrier, since LN is epilogue-folded).
// ---------------------------------------------------------------------------
__global__ __launch_bounds__(256, 4)
void k_stage1(const float* __restrict__ x, const float* __restrict__ mask,
              const ushort* __restrict__ wt1, const float* __restrict__ cb,
              ushort* __restrict__ wsg)
{
    __shared__ char sbuf[32768];   // A tile bf16(x) swz; later G bf16 [64 ch][128 pos]
    __shared__ float Ms[128], Mu[128], Rs[128];

    const int tid = threadIdx.x;
    const int g  = blockIdx.x;
    const int y  = (g >> 3) & 1;
    const int bx = (g & 7) | ((g >> 4) << 3);
    const int o0 = y * 64;
    const int w = tid >> 6, l = tid & 63;
    const int mrow = (w & 1) * 64, ncol = (w >> 1) * 64;

    long posBase, outBase; int stride;
    if (y == 0) {
        posBase = ((long)(bx >> 2)) * 512 + (long)(bx & 3) * 128;
        outBase = posBase; stride = 1;
    } else {
        posBase = ((long)(bx >> 9)) * 65536 + (bx & 511);
        outBase = (long)(bx & 511) * 512 + ((bx >> 9) * 128);
        stride = 512;
    }

    // --- B prefetch for step 0 (in flight before x loads) ---
    short8 bh[2][4], bl[2][4];
#pragma unroll
    for (int n = 0; n < 4; ++n) {
        const int row = y*128 + ncol + n*16 + (l & 15);
        const int idx = row*128 + (l >> 4)*8;
        bh[0][n] = *(const short8*)(wt1 + idx);
        bl[0][n] = *(const short8*)(wt1 + 32768 + idx);
    }

    // --- lane-linear coalesced x load -> swizzled bf16 A tile ---
    {
#pragma unroll
        for (int q = 0; q < 16; ++q) {
            const int idx = q*256 + tid;             // 16B chunk id 0..4095
            const int pos = idx >> 5, fg = idx & 31; // position row, feat group of 4
            const float4 v = *(const float4*)(x + (posBase + (long)pos*stride)*128 + fg*4);
            uint2 pk;
            pk.x = pkbf2(v.x, v.y);
            pk.y = pkbf2(v.z, v.w);
            const int col = (fg*8) ^ ((pos & 15) << 4);
            *(uint2*)(sbuf + pos*256 + col) = pk;
        }
        if (tid < 128) Ms[tid] = mask[posBase + (long)tid * stride];
    }
    __syncthreads();

    // --- stats from LDS tile (bf16-rounded; overlaps k-loop B prefetch) ---
    {
        const int r = tid >> 1, hf = tid & 1;
        float s = 0.f, ss = 0.f;
#pragma unroll
        for (int c = 0; c < 8; ++c) {
            const int col = (hf*128 + c*16) ^ ((r & 15) << 4);
            const short8 hv = *(const short8*)(sbuf + r*256 + col);
#pragma unroll
            for (int e = 0; e < 8; ++e) {
                const float tv = bf2f((ushort)hv[e]);
                s += tv; ss = fmaf(tv, tv, ss);
            }
        }
        s  += __shfl_xor(s, 1);
        ss += __shfl_xor(ss, 1);
        const float mu = s * (1.f/128.f);
        const float var = ss * (1.f/128.f) - mu*mu;
        const float rstd = rsqrtf(var + 1e-5f);
        if (hf == 0) { Mu[r] = mu; Rs[r] = rstd; }
        // no barrier: Mu/Rs consumed only after the post-MFMA barrier
    }

    f32x4 acc[4][4];
#pragma unroll
    for (int m = 0; m < 4; ++m)
#pragma unroll
        for (int n = 0; n < 4; ++n) acc[m][n] = (f32x4){0.f,0.f,0.f,0.f};

#pragma unroll
    for (int step = 0; step < 4; ++step) {
        if (step < 3) {
            const int s1 = step + 1;
#pragma unroll
            for (int n = 0; n < 4; ++n) {
                const int row = y*128 + ncol + n*16 + (l & 15);
                const int idx = row*128 + s1*32 + (l >> 4)*8;
                bh[s1 & 1][n] = *(const short8*)(wt1 + idx);
                bl[s1 & 1][n] = *(const short8*)(wt1 + 32768 + idx);
            }
        }
        short8 ah[4];
#pragma unroll
        for (int m = 0; m < 4; ++m) {
            const int pos = mrow + m*16 + (l & 15);
            const int col = (step*64 + (l >> 4)*16) ^ ((pos & 15) << 4);
            ah[m] = *(const short8*)(sbuf + pos*256 + col);
        }
#pragma unroll
        for (int m = 0; m < 4; ++m) {
#pragma unroll
            for (int n = 0; n < 4; ++n) {
                acc[m][n] = __builtin_amdgcn_mfma_f32_16x16x32_bf16(ah[m], bh[step & 1][n], acc[m][n], 0, 0, 0);
                acc[m][n] = __builtin_amdgcn_mfma_f32_16x16x32_bf16(ah[m], bl[step & 1][n], acc[m][n], 0, 0, 0);
            }
        }
    }
    __syncthreads();   // A reads done (and stats visible); sbuf becomes G

    // --- LN-folded gate: shuffle-free (pi frag n, gi frag n+2, same lane) ---
#pragma unroll
    for (int m = 0; m < 4; ++m) {
#pragma unroll
        for (int n = 0; n < 2; ++n) {
            const f32x4 aP = acc[m][n];
            const f32x4 aG = acc[m][n + 2];
            const int cl = (w >> 1)*32 + n*16 + (l & 15);
            const int och = o0 + cl;
            const float c1p = cb[och],       c2p = cb[128 + och];
            const float c1g = cb[256 + och], c2g = cb[384 + och];
            const int p0 = mrow + m*16 + (l >> 4)*4;
            float gv[4];
#pragma unroll
            for (int e = 0; e < 4; ++e) {
                const float mu = Mu[p0+e], rstd = Rs[p0+e];
                const float p_ = fmaf(rstd, aP[e] - mu*c1p, c2p);
                const float g_ = fmaf(rstd, aG[e] - mu*c1g, c2g);
                gv[e] = p_ * sigmoidf_(g_) * Ms[p0+e];
            }
            uint2 pk;
            pk.x = pkbf2(gv[0], gv[1]);
            pk.y = pkbf2(gv[2], gv[3]);
            *(uint2*)(sbuf + cl*256 + ((p0*2) ^ ((cl & 7) << 4))) = pk;
        }
    }
    __syncthreads();

    // --- cooperative plane stores: 256B-contiguous runs per plane ---
#pragma unroll
    for (int it = 0; it < 2; ++it) {
        const int u = it*256 + tid;
        const int c = u >> 3, seg = u & 7;
        ushort* hd = wsg + (long)(o0 + c) * NN + outBase + seg*16;
#pragma unroll
        for (int q = 0; q < 2; ++q) {
            const short8 v = *(const short8*)(sbuf + c*256 + ((seg*32 + q*16) ^ ((c & 7) << 4)));
            *(short8*)(hd + q*8) = v;
        }
    }
}

// ---------------------------------------------------------------------------
// Triangular einsums (unchanged): 256x256 tile, 8 waves, single-product,
// 2 buf x (A 32K | B 32K), BK=64/buffer, 8 k-iters, bf16 out.
// ---------------------------------------------------------------------------
__global__ __launch_bounds__(512, 1)
void k_einsum(const ushort* __restrict__ wsg, ushort* __restrict__ wst)
{
    const int bid = blockIdx.x;
    const int nb  = (bid & 7) * 32 + (bid >> 3);
    const int ch  = nb >> 2;
    const int bi  = (nb >> 1) & 1, bj = nb & 1;
    const int pch = (ch < 32) ? ch : ch + 32;

    const ushort* __restrict__ PH = wsg + (long)pch * NN;
    const ushort* __restrict__ QH = wsg + (long)(pch + 32) * NN;
    ushort* __restrict__ T = wst + (long)ch * NN;

    __shared__ char smem[131072];

    const int tid = threadIdx.x;
    const int w = tid >> 6, l = tid & 63;
    const int isB = w >> 2;

    const ushort* sbase = isB ? (QH + (long)bj * 131072) : (PH + (long)bi * 131072);
    int soff[8];
#pragma unroll
    for (int i = 0; i < 8; ++i) {
        const int ci  = ((w & 3) * 8 + i) * 64 + l;
        const int row = ci >> 3, s = ci & 7;
        const int c   = s ^ (row & 7);
        soff[i] = row * 512 + c * 8;
    }
    const int dbase = isB * 32768 + (w & 3) * 8192;

    f32x4 acc[4][8];
#pragma unroll
    for (int m = 0; m < 4; ++m)
#pragma unroll
        for (int n = 0; n < 8; ++n) acc[m][n] = (f32x4){0.f, 0.f, 0.f, 0.f};

    const int wr = w >> 1;
    const int wc = w & 1;

#define STAGE(buf, step)                                                           \
    {                                                                              \
        const int kOff = (step) * 64;                                              \
        _Pragma("unroll")                                                          \
        for (int i = 0; i < 8; ++i) {                                              \
            __builtin_amdgcn_global_load_lds(                                      \
                (const __attribute__((address_space(1))) void*)(sbase + soff[i] + kOff), \
                (__attribute__((address_space(3))) void*)(smem + (buf)*65536 + dbase + i*1024), \
                16, 0, 0);                                                         \
        }                                                                          \
    }

    STAGE(0, 0);
    __syncthreads();

    for (int t = 0; t < 8; ++t) {
        const int cur = t & 1;
        if (t < 7) STAGE(cur ^ 1, t + 1);

        const char* sA = (const char*)smem + cur * 65536;
        const char* sB = sA + 32768;
        const int jc = l >> 4;
        short8 ah[4][2];
#pragma unroll
        for (int m = 0; m < 4; ++m) {
            const int r = wr * 64 + m * 16 + (l & 15);
#pragma unroll
            for (int ks = 0; ks < 2; ++ks)
                ah[m][ks] = *(const short8*)(sA + r * 128 + ((((ks << 2) | jc) ^ (r & 7)) << 4));
        }
#pragma unroll
        for (int n = 0; n < 8; ++n) {
            const int r = wc * 128 + n * 16 + (l & 15);
            short8 bh0 = *(const short8*)(sB + r * 128 + (((0 | jc) ^ (r & 7)) << 4));
            short8 bh1 = *(const short8*)(sB + r * 128 + (((4 | jc) ^ (r & 7)) << 4));
#pragma unroll
            for (int m = 0; m < 4; ++m) {
                acc[m][n] = __builtin_amdgcn_mfma_f32_16x16x32_bf16(ah[m][0], bh0, acc[m][n], 0, 0, 0);
                acc[m][n] = __builtin_amdgcn_mfma_f32_16x16x32_bf16(ah[m][1], bh1, acc[m][n], 0, 0, 0);
            }
        }
        __syncthreads();
    }
#undef STAGE

    const int rbase = bi * 256 + wr * 64;
    const int cbase = bj * 256 + wc * 128;
#pragma unroll
    for (int m = 0; m < 4; ++m) {
#pragma unroll
        for (int n = 0; n < 8; ++n) {
#pragma unroll
            for (int r = 0; r < 4; ++r) {
                const int row = rbase + m * 16 + (l >> 4) * 4 + r;
                const int col = cbase + n * 16 + (l & 15);
                T[(long)row * NDIM + col] = bfbits(acc[m][n][r]);
            }
        }
    }
}

// ---------------------------------------------------------------------------
// Stage 2 (unchanged): 64-position blocks, all 128 channels, direct stores.
// ---------------------------------------------------------------------------
__global__ __launch_bounds__(256, 4)
void k_stage2(const ushort* __restrict__ wst, const float* __restrict__ mask,
              const ushort* __restrict__ wt2, const float* __restrict__ cb,
              float* __restrict__ out)
{
    __shared__ char buf[8192];     // A [64 pos][64 ch] bf16 swz
    __shared__ float Ms[64], Mu[64], Rs[64];

    const int tid = threadIdx.x;
    const long pos0 = (long)blockIdx.x * 64;
    const int w = tid >> 6, l = tid & 63;
    const int mrow = (w & 1) * 32;
    const int ncol = (w >> 1) * 128;

#pragma unroll
    for (int q = 0; q < 2; ++q) {
        const int u = q*256 + tid, d = u >> 3, p8 = (u & 7) * 8;
        const short8 v = *(const short8*)(wst + (long)d * NN + pos0 + p8);
#pragma unroll
        for (int e = 0; e < 8; ++e) {
            const int row = p8 + e;
            *(ushort*)(buf + row*128 + ((d*2) ^ ((row & 7) << 4))) = v[e];
        }
    }
    if (tid < 64) Ms[tid] = mask[pos0 + tid];
    __syncthreads();

    {
        const int r = tid >> 2, qf = tid & 3;
        float s = 0.f, ss = 0.f;
#pragma unroll
        for (int c = 0; c < 2; ++c) {
            const short8 hv = *(const short8*)(buf + r*128 + ((qf*32 + c*16) ^ ((r & 7) << 4)));
#pragma unroll
            for (int e = 0; e < 8; ++e) {
                const float tv = bf2f((ushort)hv[e]);
                s += tv; ss = fmaf(tv, tv, ss);
            }
        }
        s  += __shfl_xor(s, 1);  s  += __shfl_xor(s, 2);
        ss += __shfl_xor(ss, 1); ss += __shfl_xor(ss, 2);
        const float mu = s * (1.f/64.f);
        const float var = ss * (1.f/64.f) - mu*mu;
        const float rstd = rsqrtf(var + 1e-5f);
        if (qf == 0) { Mu[r] = mu; Rs[r] = rstd; }
    }
    __syncthreads();

    f32x4 acc[2][8];
#pragma unroll
    for (int m = 0; m < 2; ++m)
#pragma unroll
        for (int n = 0; n < 8; ++n) acc[m][n] = (f32x4){0.f,0.f,0.f,0.f};

#pragma unroll
    for (int step = 0; step < 2; ++step) {
        short8 ah[2];
#pragma unroll
        for (int m = 0; m < 2; ++m) {
            const int pos = mrow + m*16 + (l & 15);
            const int col = (step*64 + (l >> 4)*16) ^ ((pos & 7) << 4);
            ah[m] = *(const short8*)(buf + pos*128 + col);
        }
#pragma unroll
        for (int n = 0; n < 8; ++n) {
            const int row = ncol + n*16 + (l & 15);
            const int idx = row*64 + step*32 + (l >> 4)*8;
            const short8 bh = *(const short8*)(wt2 + idx);
            const short8 bl = *(const short8*)(wt2 + 16384 + idx);
#pragma unroll
            for (int m = 0; m < 2; ++m) {
                acc[m][n] = __builtin_amdgcn_mfma_f32_16x16x32_bf16(ah[m], bh, acc[m][n], 0, 0, 0);
                acc[m][n] = __builtin_amdgcn_mfma_f32_16x16x32_bf16(ah[m], bl, acc[m][n], 0, 0, 0);
            }
        }
    }

    // --- LN-folded gate: shuffle-free (pi frag n, gi frag n+4) ---
#pragma unroll
    for (int m = 0; m < 2; ++m) {
#pragma unroll
        for (int n = 0; n < 4; ++n) {
            const f32x4 aP = acc[m][n];
            const f32x4 aG = acc[m][n + 4];
            const int och = (w >> 1)*64 + n*16 + (l & 15);
            const float c1p = cb[och],       c2p = cb[128 + och];
            const float c1g = cb[256 + och], c2g = cb[384 + och];
            const int p0 = mrow + m*16 + (l >> 4)*4;
#pragma unroll
            for (int e = 0; e < 4; ++e) {
                const float mu = Mu[p0+e], rstd = Rs[p0+e];
                const float p_ = fmaf(rstd, aP[e] - mu*c1p, c2p);
                const float g_ = fmaf(rstd, aG[e] - mu*c1g, c2g);
                out[(pos0 + p0 + e)*128 + och] = p_ * sigmoidf_(g_) * Ms[p0+e];
            }
        }
    }
}

// ---------------------------------------------------------------------------
extern "C" void kernel_launch(void* const* d_in, const int* in_sizes, int n_in,
                              void* d_out, int out_size, void* d_ws, size_t ws_size,
                              hipStream_t stream)
{
    const float* x     = (const float*)d_in[0];
    const float* mask  = (const float*)d_in[1];
    const float* ln1_w = (const float*)d_in[2];
    const float* ln1_b = (const float*)d_in[3];
    const float* pi_w  = (const float*)d_in[4];
    const float* pi_b  = (const float*)d_in[5];
    const float* gi_w  = (const float*)d_in[6];
    const float* gi_b  = (const float*)d_in[7];
    const float* ln2_w = (const float*)d_in[8];
    const float* ln2_b = (const float*)d_in[9];
    const float* po_w  = (const float*)d_in[10];
    const float* po_b  = (const float*)d_in[11];
    const float* go_w  = (const float*)d_in[12];
    const float* go_b  = (const float*)d_in[13];

    ushort* wsg  = (ushort*)d_ws;                               // 128 bf16 g planes (64 MiB)
    ushort* wstu = (ushort*)((char*)d_ws + (long)128 * NN * 2); // 64 bf16 t planes (32 MiB)
    ushort* wt1  = wstu;                                        // transient (pre-einsum)
    float*  cb1  = (float*)(wt1 + 65536);
    ushort* wt2  = wsg;                                         // transient (post-einsum)
    float*  cb2  = (float*)(wt2 + 32768);

    k_prep<<<66, 256, 0, stream>>>(pi_w, gi_w, ln1_w, ln1_b, pi_b, gi_b, 128, wt1, cb1);
    k_stage1<<<4096, 256, 0, stream>>>(x, mask, wt1, cb1, wsg);
    k_einsum<<<256, 512, 0, stream>>>(wsg, wstu);
    k_prep<<<34, 256, 0, stream>>>(po_w, go_w, ln2_w, ln2_b, po_b, go_b, 64, wt2, cb2);
    k_stage2<<<4096, 256, 0, stream>>>(wstu, mask, wt2, cb2, (float*)d_out);
}